// Round 1
// baseline (547.774 us; speedup 1.0000x reference)
//
#include <hip/hip_runtime.h>
#include <cstdint>
#include <cstddef>

// ---------------- problem constants ----------------
#define TGT   24
#define BS    16
#define SRC   400
#define VOCABN 32000
#define DIM   256
#define NROW  (TGT*BS)   // 384

typedef __bf16 bf16_t;
typedef __bf16 v8bf __attribute__((ext_vector_type(8)));
typedef float  v4f  __attribute__((ext_vector_type(4)));

__device__ __forceinline__ float fast_tanh(float x) {
    // monotone, no NaN for large |x|: e->0 => -1, e->inf => +1
    float e = __expf(2.f*x);
    return 1.f - 2.f/(e + 1.f);
}

// ---------------- prep: dtype conversions / transposes / gather ----------------
__global__ void k_prep(const float* __restrict__ Whh, const float* __restrict__ Wad,
                       const float* __restrict__ he,  const float* __restrict__ Wemb,
                       const float* __restrict__ Wproj, const float* __restrict__ Wae,
                       const float* __restrict__ Wih, const int* __restrict__ inputs,
                       bf16_t* o_whh, bf16_t* o_wadT, bf16_t* o_he, bf16_t* o_heT,
                       bf16_t* o_wae, bf16_t* o_wih, bf16_t* o_wprojT, bf16_t* o_embA)
{
    const long S0=262144, S1=65536, S2=1638400, S3=1638400, S4=65536, S5=262144, S6=196608, S7=98304;
    const long total = S0+S1+S2+S3+S4+S5+S6+S7;
    for (long i = (long)blockIdx.x*blockDim.x + threadIdx.x; i < total;
         i += (long)gridDim.x*blockDim.x) {
        long j = i;
        if (j < S0) { o_whh[j] = (bf16_t)Whh[j]; continue; }           j -= S0;
        if (j < S1) { long n = j>>8, k = j&255; o_wadT[j] = (bf16_t)Wad[k*DIM + n]; continue; } j -= S1;
        if (j < S2) { o_he[j] = (bf16_t)he[j]; continue; }             j -= S2;
        if (j < S3) { // heT[b][d][s] = he[(s*BS+b)*DIM+d]
            long b = j / 102400, rem = j % 102400, d = rem / 400, s = rem % 400;
            o_heT[j] = (bf16_t)he[(s*BS + b)*DIM + d]; continue; }     j -= S3;
        if (j < S4) { o_wae[j] = (bf16_t)Wae[j]; continue; }           j -= S4;
        if (j < S5) { o_wih[j] = (bf16_t)Wih[j]; continue; }           j -= S5;
        if (j < S6) { long n = j>>8, k = j&255; o_wprojT[j] = (bf16_t)Wproj[k*768 + n]; continue; } j -= S6;
        { long r = j>>8, k = j&255; o_embA[j] = (bf16_t)Wemb[(long)inputs[r]*DIM + k]; }
    }
}

// ---------------- generic bf16 MFMA GEMM tile, 128x128, BK=32 (device body) ----
// C[M,N] = A[M,K] @ B[N,K]^T  (row-major, K-contiguous). A32!=null: A read fp32.
// mode 0: fp32 out + bias0 + bias1
// mode 1: bf16 out, tanh
// mode 2: bf16 out
// mode 3: exp(v+bias0), pad col -> 0, accumulate row sums into rsum (atomics)
// mode 4: fp32 out + bias0 + bias1, written TRANSPOSED-per-gate for the LSTM:
//         out[row*1024 + (col&255)*4 + (col>>8)]   (N must be 1024)
__device__ __forceinline__ void gemm_tile(
    const int tid, bf16_t* As, bf16_t* Bs,
    const bf16_t* __restrict__ A, const float* __restrict__ A32,
    const bf16_t* __restrict__ B,
    const int tileIdx, const int N, const int K, const int Ntiles, const int mode,
    float* __restrict__ outF, bf16_t* __restrict__ outB,
    const float* __restrict__ bias0, const float* __restrict__ bias1,
    const int* __restrict__ padp, float* __restrict__ rsum)
{
    const int mt   = tileIdx / Ntiles, nt = tileIdx % Ntiles;
    const int m0   = mt*128, n0 = nt*128;
    const int lane = tid & 63, wave = tid >> 6;
    const int wm   = wave >> 1, wn = wave & 1;
    const int quad = lane >> 4, l16 = lane & 15;

    v4f acc[4][4];
#pragma unroll
    for (int i=0;i<4;i++)
#pragma unroll
        for (int j=0;j<4;j++) acc[i][j] = (v4f){0.f,0.f,0.f,0.f};

    const int srow = tid >> 1, shalf = tid & 1;       // staging: 2 threads/row
    const bf16_t* Ag   = A   ? A   + (size_t)(m0+srow)*K + shalf*16 : nullptr;
    const float*  Ag32 = A32 ? A32 + (size_t)(m0+srow)*K + shalf*16 : nullptr;
    const bf16_t* Bg = B + (size_t)(n0+srow)*K + shalf*16;
    bf16_t* AsW = &As[srow*40 + shalf*16];
    bf16_t* BsW = &Bs[srow*40 + shalf*16];

    for (int kc = 0; kc < K; kc += 32) {
        __syncthreads();
        uint4 b0 = *(const uint4*)(Bg + kc);
        uint4 b1 = *(const uint4*)(Bg + kc + 8);
        if (A32) {
            float4 f0 = *(const float4*)(Ag32 + kc);
            float4 f1 = *(const float4*)(Ag32 + kc + 4);
            float4 f2 = *(const float4*)(Ag32 + kc + 8);
            float4 f3 = *(const float4*)(Ag32 + kc + 12);
            v8bf u0, u1;
            u0[0]=(bf16_t)f0.x; u0[1]=(bf16_t)f0.y; u0[2]=(bf16_t)f0.z; u0[3]=(bf16_t)f0.w;
            u0[4]=(bf16_t)f1.x; u0[5]=(bf16_t)f1.y; u0[6]=(bf16_t)f1.z; u0[7]=(bf16_t)f1.w;
            u1[0]=(bf16_t)f2.x; u1[1]=(bf16_t)f2.y; u1[2]=(bf16_t)f2.z; u1[3]=(bf16_t)f2.w;
            u1[4]=(bf16_t)f3.x; u1[5]=(bf16_t)f3.y; u1[6]=(bf16_t)f3.z; u1[7]=(bf16_t)f3.w;
            *(v8bf*)AsW = u0; *(v8bf*)(AsW+8) = u1;
        } else {
            uint4 a0 = *(const uint4*)(Ag + kc);
            uint4 a1 = *(const uint4*)(Ag + kc + 8);
            *(uint4*)AsW = a0; *(uint4*)(AsW+8) = a1;
        }
        *(uint4*)BsW = b0; *(uint4*)(BsW+8) = b1;
        __syncthreads();
        v8bf af[4], bb[4];
#pragma unroll
        for (int i=0;i<4;i++) {
            af[i] = *(const v8bf*)&As[(wm*64 + i*16 + l16)*40 + quad*8];
            bb[i] = *(const v8bf*)&Bs[(wn*64 + i*16 + l16)*40 + quad*8];
        }
#pragma unroll
        for (int i=0;i<4;i++)
#pragma unroll
            for (int j=0;j<4;j++)
                acc[i][j] = __builtin_amdgcn_mfma_f32_16x16x32_bf16(af[i], bb[j], acc[i][j], 0,0,0);
    }

    const int pad = padp ? *padp : -1;
    float* rs = (float*)As;          // LDS reuse for mode-3 row partial sums
    if (mode == 3) {
        __syncthreads();             // everyone past last As read
        if (tid < 128) rs[tid] = 0.f;
        __syncthreads();
    }
#pragma unroll
    for (int i=0;i<4;i++) {
        float rloc[4] = {0.f,0.f,0.f,0.f};
#pragma unroll
        for (int j=0;j<4;j++) {
#pragma unroll
            for (int r=0;r<4;r++) {
                const int gr = m0 + wm*64 + i*16 + quad*4 + r;   // C/D row = quad*4+reg
                const int gc = n0 + wn*64 + j*16 + l16;          // C/D col = lane&15
                const float v = acc[i][j][r];
                if (mode == 0)      outF[(size_t)gr*N + gc] = v + bias0[gc] + bias1[gc];
                else if (mode == 1) outB[(size_t)gr*N + gc] = (bf16_t)fast_tanh(v);
                else if (mode == 2) outB[(size_t)gr*N + gc] = (bf16_t)v;
                else if (mode == 4) outF[(size_t)gr*N + (gc & 255)*4 + (gc >> 8)] = v + bias0[gc] + bias1[gc];
                else {
                    float ex = (gc == pad) ? 0.f : __expf(v + bias0[gc]);
                    outF[(size_t)gr*N + gc] = ex;
                    rloc[r] += ex;
                }
            }
        }
        if (mode == 3) {
#pragma unroll
            for (int r=0;r<4;r++)
                atomicAdd(&rs[wm*64 + i*16 + quad*4 + r], rloc[r]);
        }
    }
    if (mode == 3) {
        __syncthreads();
        if (tid < 128) atomicAdd(&rsum[m0 + tid], rs[tid]);
    }
}

// standalone 256-thread GEMM wrapper (used for xg mode-4 and the big mode-3)
__global__ __launch_bounds__(256) void k_gemm(
    const bf16_t* __restrict__ A, const float* __restrict__ A32,
    const bf16_t* __restrict__ B,
    int M, int N, int K, int Ntiles, int mode,
    float* outF, bf16_t* outB,
    const float* __restrict__ bias0, const float* __restrict__ bias1,
    const int* __restrict__ padp, float* __restrict__ rsum)
{
    (void)M;
    __shared__ bf16_t As[128*40];
    __shared__ bf16_t Bs[128*40];
    gemm_tile(threadIdx.x, As, Bs, A, A32, B, blockIdx.x, N, K, Ntiles, mode,
              outF, outB, bias0, bias1, padp, rsum);
}

// ---------------- sequential LSTM chain body: ONE block, weight-resident -------
// 512 threads = 8 waves (2/SIMD, 256-VGPR cap). Wave w owns d-slice [w*32,w*32+32).
// Gate rows g*256+d: g=0,1 in registers (128 VGPR), g=2 streamed per-kc from L2
// (loop-invariant addresses, small live set), g=3 in LDS (128 KB).
// xg is pre-transposed to [row][d][gate] so each thread prefetches 8 coalesced
// float4's at the top of the step (latency hidden under the MFMA loop).
__device__ void lstm_body(char* sh,
    const bf16_t* __restrict__ Whh, const float* __restrict__ xgT,
    const float* __restrict__ h0, const float* __restrict__ c0,
    float* __restrict__ hallF, bf16_t* __restrict__ hallB)
{
    bf16_t* wlds = (bf16_t*)sh;              // 131072 B: gate-3 tiles
    bf16_t* hhi  = (bf16_t*)(sh + 131072);   // [16][264]
    bf16_t* hlo  = (bf16_t*)(sh + 139520);   // [16][264]

    const int tid = threadIdx.x;
    const int w = tid >> 6, lane = tid & 63;
    const int l16 = lane & 15, quad = lane >> 4;

    // preload gate-3 weights into LDS (conflict-free layout)
    for (int idx = tid; idx < 8192; idx += 512) {
        int tl = idx >> 9, u = idx & 511;
        int kc = u >> 6, r16 = (u >> 2) & 15, q = u & 3;
        int grow = 768 + (tl >> 1)*32 + (tl & 1)*16 + r16;
        *(uint4*)&wlds[idx*8] = *(const uint4*)&Whh[(size_t)grow*DIM + kc*32 + q*8];
    }
    // preload gate-0/1 weights into registers: wreg[g*2+hf][kc]
    v8bf wreg[4][8];
#pragma unroll
    for (int g = 0; g < 2; ++g)
#pragma unroll
      for (int hf = 0; hf < 2; ++hf)
#pragma unroll
        for (int kc = 0; kc < 8; ++kc)
            wreg[g*2+hf][kc] = *(const v8bf*)&Whh[(size_t)(g*256 + w*32 + hf*16 + l16)*DIM + kc*32 + quad*8];

    for (int i = tid; i < 4096; i += 512) {
        int b = i >> 8, d = i & 255;
        float v = h0[b*DIM + d];
        bf16_t hi = (bf16_t)v;
        hhi[b*264+d] = hi; hlo[b*264+d] = (bf16_t)(v - (float)hi);
    }
    float c[2][4];
#pragma unroll
    for (int hf = 0; hf < 2; ++hf)
#pragma unroll
      for (int r = 0; r < 4; ++r)
        c[hf][r] = c0[(quad*4 + r)*DIM + w*32 + hf*16 + l16];
    __syncthreads();

    const bf16_t* g2base = Whh + (size_t)(512 + w*32 + l16)*DIM + quad*8;
    for (int step = 0; step < TGT; ++step) {
        // xg prefetch (independent of h): 8 coalesced float4 loads, used after MFMA
        float4 xv[2][4];
#pragma unroll
        for (int hf = 0; hf < 2; ++hf) {
            const int d = w*32 + hf*16 + l16;
#pragma unroll
            for (int r = 0; r < 4; ++r) {
                const int b = quad*4 + r;
                xv[hf][r] = *(const float4*)(xgT + ((size_t)(step*BS + b)*DIM + d)*4);
            }
        }

        v4f acc[4][2];
#pragma unroll
        for (int g = 0; g < 4; ++g)
#pragma unroll
          for (int hf = 0; hf < 2; ++hf) acc[g][hf] = (v4f){0.f,0.f,0.f,0.f};

#pragma unroll
        for (int kc = 0; kc < 8; ++kc) {
            v8bf w20 = *(const v8bf*)(g2base + (size_t)kc*32);               // gate-2 stream (L2-hot)
            v8bf w21 = *(const v8bf*)(g2base + (size_t)16*DIM + kc*32);
            v8bf ahi = *(const v8bf*)&hhi[l16*264 + kc*32 + quad*8];
            v8bf alo = *(const v8bf*)&hlo[l16*264 + kc*32 + quad*8];
#pragma unroll
            for (int g = 0; g < 2; ++g)
#pragma unroll
              for (int hf = 0; hf < 2; ++hf) {
                acc[g][hf] = __builtin_amdgcn_mfma_f32_16x16x32_bf16(ahi, wreg[g*2+hf][kc], acc[g][hf], 0,0,0);
                acc[g][hf] = __builtin_amdgcn_mfma_f32_16x16x32_bf16(alo, wreg[g*2+hf][kc], acc[g][hf], 0,0,0);
              }
            acc[2][0] = __builtin_amdgcn_mfma_f32_16x16x32_bf16(ahi, w20, acc[2][0], 0,0,0);
            acc[2][0] = __builtin_amdgcn_mfma_f32_16x16x32_bf16(alo, w20, acc[2][0], 0,0,0);
            acc[2][1] = __builtin_amdgcn_mfma_f32_16x16x32_bf16(ahi, w21, acc[2][1], 0,0,0);
            acc[2][1] = __builtin_amdgcn_mfma_f32_16x16x32_bf16(alo, w21, acc[2][1], 0,0,0);
            v8bf bl0 = *(const v8bf*)&wlds[(((w*2+0)*8 + kc)*16 + l16)*32 + quad*8];
            v8bf bl1 = *(const v8bf*)&wlds[(((w*2+1)*8 + kc)*16 + l16)*32 + quad*8];
            acc[3][0] = __builtin_amdgcn_mfma_f32_16x16x32_bf16(ahi, bl0, acc[3][0], 0,0,0);
            acc[3][0] = __builtin_amdgcn_mfma_f32_16x16x32_bf16(alo, bl0, acc[3][0], 0,0,0);
            acc[3][1] = __builtin_amdgcn_mfma_f32_16x16x32_bf16(ahi, bl1, acc[3][1], 0,0,0);
            acc[3][1] = __builtin_amdgcn_mfma_f32_16x16x32_bf16(alo, bl1, acc[3][1], 0,0,0);
        }
        __syncthreads();   // all reads of old h complete
#pragma unroll
        for (int hf = 0; hf < 2; ++hf) {
            const int d = w*32 + hf*16 + l16;
#pragma unroll
            for (int r = 0; r < 4; ++r) {
                const int b = quad*4 + r;
                const float gi = acc[0][hf][r] + xv[hf][r].x;
                const float gf = acc[1][hf][r] + xv[hf][r].y;
                const float gg = acc[2][hf][r] + xv[hf][r].z;
                const float go = acc[3][hf][r] + xv[hf][r].w;
                const float si = 1.f/(1.f+__expf(-gi));
                const float sf = 1.f/(1.f+__expf(-gf));
                const float so = 1.f/(1.f+__expf(-go));
                const float cn = sf*c[hf][r] + si*fast_tanh(gg);
                const float hn = so*fast_tanh(cn);
                c[hf][r] = cn;
                const bf16_t hi = (bf16_t)hn;
                hhi[b*264+d] = hi; hlo[b*264+d] = (bf16_t)(hn - (float)hi);
                hallF[(size_t)(step*BS + b)*DIM + d] = hn;
                hallB[(size_t)(step*BS + b)*DIM + d] = hi;
            }
        }
        __syncthreads();
    }
}

// ---------------- fused: block 0 = LSTM chain, other blocks = independent GEMMs -
// Blocks 1..750: W_out = tanh(W_emb @ W_proj) tiles (2 tiles per block, one per
// 256-thread half). Blocks 751..800: ke = h_e @ W_ae^T tiles. These are fully
// independent of the LSTM, and previously serialized behind it while 255 CUs idled.
__global__ __launch_bounds__(512, 2) void k_fused(
    const bf16_t* __restrict__ Whh, const float* __restrict__ xgT,
    const float* __restrict__ h0, const float* __restrict__ c0,
    float* __restrict__ hallF, bf16_t* __restrict__ hallB,
    const float* __restrict__ Wemb, const bf16_t* __restrict__ wprojT, bf16_t* __restrict__ woutB,
    const bf16_t* __restrict__ heA, const bf16_t* __restrict__ waeB, bf16_t* __restrict__ keB)
{
    __shared__ __align__(16) char sh[147968];
    const int bid = blockIdx.x;
    if (bid == 0) {
        lstm_body(sh, Whh, xgT, h0, c0, hallF, hallB);
        return;
    }
    const int half = threadIdx.x >> 8;        // wave 0-3 vs 4-7: two independent tiles
    const int tid  = threadIdx.x & 255;
    bf16_t* As = (bf16_t*)(sh + half*20480);
    bf16_t* Bs = (bf16_t*)(sh + half*20480 + 10240);
    if (bid <= 750) {      // W_out: M=32000, N=768, K=256, Ntiles=6 -> 1500 tiles
        const int tile = (bid - 1)*2 + half;
        gemm_tile(tid, As, Bs, nullptr, Wemb, wprojT, tile, 768, 256, 6, 1,
                  nullptr, woutB, nullptr, nullptr, nullptr, nullptr);
    } else {               // ke: M=6400, N=256, K=256, Ntiles=2 -> 100 tiles
        const int tile = (bid - 751)*2 + half;
        gemm_tile(tid, As, Bs, heA, nullptr, waeB, tile, 256, 256, 2, 2,
                  nullptr, keB, nullptr, nullptr, nullptr, nullptr);
    }
}

// ---------------- expE[t,b,s] = exp(ke[s,b,:] . h[t,b,:]) (device body) --------
__device__ __forceinline__ void escore_body(const int blk, const int tid, float* hS,
    const bf16_t* __restrict__ ke, const float* __restrict__ hallF, float* __restrict__ expE)
{
    const int t = blk >> 4, b = blk & 15;
    hS[tid] = hallF[(size_t)(t*BS + b)*DIM + tid];
    __syncthreads();
    for (int s = tid; s < SRC; s += 256) {
        const v8bf* kp = (const v8bf*)(ke + ((size_t)s*BS + b)*DIM);
        float e = 0.f;
#pragma unroll 8
        for (int m=0;m<32;m++) {
            v8bf kv = kp[m];
#pragma unroll
            for (int i=0;i<8;i++) e += (float)kv[i]*hS[m*8+i];
        }
        expE[((size_t)t*BS + b)*SRC + s] = __expf(e);
    }
}

// fused escore + qd GEMM (qd = h_all @ W_attn_dec, 6 tiles) — both depend only on
// the LSTM outputs, so they share one launch.
__global__ __launch_bounds__(256) void k_esq(
    const bf16_t* __restrict__ ke, const float* __restrict__ hallF, float* __restrict__ expE,
    const bf16_t* __restrict__ hallB, const bf16_t* __restrict__ wadT, bf16_t* __restrict__ qdG)
{
    __shared__ __align__(16) char shb[20480];
    if (blockIdx.x < NROW) {
        escore_body(blockIdx.x, threadIdx.x, (float*)shb, ke, hallF, expE);
        return;
    }
    gemm_tile(threadIdx.x, (bf16_t*)shb, (bf16_t*)(shb + 10240), hallB, nullptr, wadT,
              blockIdx.x - NROW, 256, 256, 2, 2, nullptr, qdG, nullptr, nullptr, nullptr, nullptr);
}

// ---------------- per-(t,b) attention tail ----------------
__global__ __launch_bounds__(256) void k_attn2(
    const float* __restrict__ expE, const bf16_t* __restrict__ heT,
    const float* __restrict__ hallF, const bf16_t* __restrict__ qdG,
    const float* __restrict__ wu, const float* __restrict__ bu,
    bf16_t* __restrict__ feat, float* __restrict__ Ae, float* __restrict__ ps)
{
    const int t = blockIdx.x >> 4, b = blockIdx.x & 15;
    const int tid = threadIdx.x;
    __shared__ float hS[DIM], qdS[DIM], eeS[SRC], adS[TGT];
    __shared__ float red[4], misc[2];

    hS[tid]  = hallF[(size_t)(t*BS + b)*DIM + tid];
    qdS[tid] = (float)qdG[(size_t)(t*BS + b)*DIM + tid];
    __syncthreads();

    for (int s = tid; s < SRC; s += 256) {
        float prev = 0.f;
        for (int tp = 0; tp < t; ++tp) prev += expE[((size_t)tp*BS + b)*SRC + s];
        float my = expE[((size_t)t*BS + b)*SRC + s];
        eeS[s] = (t == 0) ? my : my / prev;
    }
    __syncthreads();
    {   // esum
        float pa = 0.f;
        for (int s = tid; s < SRC; s += 256) pa += eeS[s];
#pragma unroll
        for (int o=32;o>0;o>>=1) pa += __shfl_down(pa, o);
        if ((tid & 63) == 0) red[tid>>6] = pa;
        __syncthreads();
        if (tid == 0) misc[0] = 1.f/(red[0]+red[1]+red[2]+red[3]);
        __syncthreads();
    }
    const float inv_es = misc[0];
    for (int s = tid; s < SRC; s += 256)
        Ae[((size_t)t*BS + b)*SRC + s] = eeS[s] * inv_es;

    float ce;
    {
        const v8bf* hp = (const v8bf*)(heT + ((size_t)b*DIM + tid)*SRC);
        float acc = 0.f;
#pragma unroll 10
        for (int m=0;m<50;m++) {
            v8bf hv = hp[m];
#pragma unroll
            for (int i=0;i<8;i++) acc += (float)hv[i]*eeS[m*8+i];
        }
        ce = acc * inv_es;
    }

    {
        const int wv = tid >> 6, ln = tid & 63;
        for (int tau = wv; tau <= t; tau += 4) {
            float4 a = *(const float4*)(hallF + ((size_t)(tau*BS + b))*DIM + ln*4);
            float e = a.x*qdS[ln*4] + a.y*qdS[ln*4+1] + a.z*qdS[ln*4+2] + a.w*qdS[ln*4+3];
#pragma unroll
            for (int o=32;o>0;o>>=1) e += __shfl_down(e, o);
            if (ln == 0) adS[tau] = __expf(e);
        }
    }
    __syncthreads();
    if (tid < 64) {
        float v = (tid <= t) ? adS[tid] : 0.f;
#pragma unroll
        for (int o=32;o>0;o>>=1) v += __shfl_down(v, o);
        if (tid == 0) misc[1] = 1.f/v;
    }
    __syncthreads();
    float cd = 0.f;
    for (int tau = 0; tau <= t; ++tau)
        cd += adS[tau] * hallF[((size_t)(tau*BS + b))*DIM + tid];
    cd *= misc[1];
    if (t == 0) cd = 0.f;

    const float hd = hS[tid];
    const size_t fr = ((size_t)t*BS + b)*768;
    feat[fr + tid]       = (bf16_t)hd;
    feat[fr + 256 + tid] = (bf16_t)ce;
    feat[fr + 512 + tid] = (bf16_t)cd;
    float pw = hd*wu[tid] + ce*wu[256 + tid] + cd*wu[512 + tid];
#pragma unroll
    for (int o=32;o>0;o>>=1) pw += __shfl_down(pw, o);
    if ((tid & 63) == 0) red[tid>>6] = pw;
    __syncthreads();
    if (tid == 0) {
        float s = red[0]+red[1]+red[2]+red[3];
        ps[t*BS + b] = 1.f/(1.f+__expf(-(s + bu[0])));
    }
}

// ---------------- scores = exp_logits * ps[r]/rsum[r] (scale folded in) --------
__global__ void k_norm(float* __restrict__ out, const float* __restrict__ rsum,
                       const float* __restrict__ ps)
{
    const long n4 = (long)NROW*VOCABN/4;
    for (long i = (long)blockIdx.x*blockDim.x + threadIdx.x; i < n4;
         i += (long)gridDim.x*blockDim.x) {
        const long r = (i*4)/VOCABN;
        float4 v = ((float4*)out)[i];
        const float sc = ps[r]/rsum[r];
        v.x*=sc; v.y*=sc; v.z*=sc; v.w*=sc;
        ((float4*)out)[i] = v;
    }
}

// ---------------- copy mechanism scatter ----------------
__global__ __launch_bounds__(256) void k_copy(float* __restrict__ out,
                                              const int* __restrict__ src,
                                              const float* __restrict__ Ae,
                                              const float* __restrict__ ps)
{
    const int r = blockIdx.x;        // r = t*BS + b
    const int b = r & (BS-1);
    const float p = ps[r];
    for (int s = threadIdx.x; s < SRC; s += 256) {
        const int v = src[s*BS + b];
        atomicAdd(&out[(size_t)r*VOCABN + v], Ae[(size_t)r*SRC + s] * p);
    }
}

// ---------------- workspace layout (bytes, 16B-aligned) ----------------
#define O_WHH    0u
#define O_WADT   524288u
#define O_HEBF   655360u
#define O_HET    3932160u
#define O_KE     7208960u
#define O_WAE    10485760u
#define O_WPROJT 10616832u
#define O_WIH    11010048u
#define O_EMBA   11534336u
#define O_WOUT   11730944u
#define O_XG     60882944u
#define O_HALLF  62455808u
#define O_HALLB  62849024u
#define O_QD     63045632u
#define O_EXPE   63242240u
#define O_FEAT   63856640u
#define O_AE     64446464u
#define O_PS     65060864u
#define O_RSUM   65063936u   // 1536 B, zeroed each call

extern "C" void kernel_launch(void* const* d_in, const int* in_sizes, int n_in,
                              void* d_out, int out_size, void* d_ws, size_t ws_size,
                              hipStream_t stream)
{
    const int*   inputs = (const int*)  d_in[0];
    const int*   src    = (const int*)  d_in[1];
    const float* h_e    = (const float*)d_in[2];
    const float* h0     = (const float*)d_in[3];
    const float* c0     = (const float*)d_in[4];
    const float* W_emb  = (const float*)d_in[5];
    const float* W_ih   = (const float*)d_in[6];
    const float* b_ih   = (const float*)d_in[7];
    const float* W_hh   = (const float*)d_in[8];
    const float* b_hh   = (const float*)d_in[9];
    const float* W_ae   = (const float*)d_in[10];
    const float* W_ad   = (const float*)d_in[11];
    const float* W_proj = (const float*)d_in[12];
    const float* W_u    = (const float*)d_in[13];
    const float* b_u    = (const float*)d_in[14];
    const float* b_out  = (const float*)d_in[15];
    const int*   pad_id = (const int*)  d_in[16];

    char* w = (char*)d_ws;
    bf16_t* whh_bf  = (bf16_t*)(w + O_WHH);
    bf16_t* wadT_bf = (bf16_t*)(w + O_WADT);
    bf16_t* he_bf   = (bf16_t*)(w + O_HEBF);
    bf16_t* heT_bf  = (bf16_t*)(w + O_HET);
    bf16_t* ke_bf   = (bf16_t*)(w + O_KE);
    bf16_t* wae_bf  = (bf16_t*)(w + O_WAE);
    bf16_t* wprojT  = (bf16_t*)(w + O_WPROJT);
    bf16_t* wih_bf  = (bf16_t*)(w + O_WIH);
    bf16_t* embA_bf = (bf16_t*)(w + O_EMBA);
    bf16_t* wout_bf = (bf16_t*)(w + O_WOUT);
    float*  xg      = (float*) (w + O_XG);      // holds xgT: [row][d][gate]
    float*  hallF   = (float*) (w + O_HALLF);
    bf16_t* hallB   = (bf16_t*)(w + O_HALLB);
    bf16_t* qdG     = (bf16_t*)(w + O_QD);
    float*  expE    = (float*) (w + O_EXPE);
    bf16_t* feat_bf = (bf16_t*)(w + O_FEAT);
    float*  Ae      = (float*) (w + O_AE);
    float*  ps      = (float*) (w + O_PS);
    float*  rsum    = (float*) (w + O_RSUM);
    float*  out     = (float*)d_out;

    k_prep<<<1024, 256, 0, stream>>>(W_hh, W_ad, h_e, W_emb, W_proj, W_ae, W_ih, inputs,
                                     whh_bf, wadT_bf, he_bf, heT_bf,
                                     wae_bf, wih_bf, wprojT, embA_bf);
    hipMemsetAsync(w + O_RSUM, 0, 1536, stream);
    // xgT = (embA @ W_ih^T + b_ih + b_hh) transposed-per-gate  (M=384, N=1024, K=256)
    k_gemm<<<24, 256, 0, stream>>>(embA_bf, nullptr, wih_bf, NROW, 1024, 256, 8, 4,
                                   xg, nullptr, b_ih, b_hh, nullptr, nullptr);
    // fused: sequential LSTM (block 0) + W_out GEMM (blocks 1-750) + ke GEMM (751-800)
    k_fused<<<801, 512, 0, stream>>>(whh_bf, xg, h0, c0, hallF, hallB,
                                     W_emb, wprojT, wout_bf,
                                     he_bf, wae_bf, ke_bf);
    // fused: escore (blocks 0-383) + qd GEMM (blocks 384-389)
    k_esq<<<NROW + 6, 256, 0, stream>>>(ke_bf, hallF, expE, hallB, wadT_bf, qdG);
    k_attn2<<<NROW, 256, 0, stream>>>(expE, heT_bf, hallF, qdG, W_u, b_u,
                                      feat_bf, Ae, ps);
    // exp(logits + b_out), pad -> 0, + fused row sums  (M=384, N=32000, K=768)
    k_gemm<<<750, 256, 0, stream>>>(feat_bf, nullptr, wout_bf, NROW, VOCABN, 768, 250, 3,
                                    out, nullptr, b_out, nullptr, pad_id, rsum);
    k_norm<<<2048, 256, 0, stream>>>(out, rsum, ps);
    k_copy<<<NROW, 256, 0, stream>>>(out, src, Ae, ps);
}

// Round 2
// 531.756 us; speedup vs baseline: 1.0301x; 1.0301x over previous
//
#include <hip/hip_runtime.h>
#include <cstdint>
#include <cstddef>

// ---------------- problem constants ----------------
#define TGT   24
#define BS    16
#define SRC   400
#define VOCABN 32000
#define DIM   256
#define NROW  (TGT*BS)   // 384

typedef __bf16 bf16_t;
typedef __bf16 v8bf __attribute__((ext_vector_type(8)));
typedef float  v4f  __attribute__((ext_vector_type(4)));

__device__ __forceinline__ float fast_tanh(float x) {
    // monotone, no NaN for large |x|: e->0 => -1, e->inf => +1
    float e = __expf(2.f*x);
    return 1.f - 2.f/(e + 1.f);
}

// ---------------- prep: dtype conversions / transposes / gather ----------------
__global__ void k_prep(const float* __restrict__ Whh, const float* __restrict__ Wad,
                       const float* __restrict__ he,  const float* __restrict__ Wemb,
                       const float* __restrict__ Wproj, const float* __restrict__ Wae,
                       const float* __restrict__ Wih, const int* __restrict__ inputs,
                       bf16_t* o_whh, bf16_t* o_wadT, bf16_t* o_he, bf16_t* o_heT,
                       bf16_t* o_wae, bf16_t* o_wih, bf16_t* o_wprojT, bf16_t* o_embA)
{
    const long S0=262144, S1=65536, S2=1638400, S3=1638400, S4=65536, S5=262144, S6=196608, S7=98304;
    const long total = S0+S1+S2+S3+S4+S5+S6+S7;
    for (long i = (long)blockIdx.x*blockDim.x + threadIdx.x; i < total;
         i += (long)gridDim.x*blockDim.x) {
        long j = i;
        if (j < S0) { o_whh[j] = (bf16_t)Whh[j]; continue; }           j -= S0;
        if (j < S1) { long n = j>>8, k = j&255; o_wadT[j] = (bf16_t)Wad[k*DIM + n]; continue; } j -= S1;
        if (j < S2) { o_he[j] = (bf16_t)he[j]; continue; }             j -= S2;
        if (j < S3) { // heT[b][d][s] = he[(s*BS+b)*DIM+d]
            long b = j / 102400, rem = j % 102400, d = rem / 400, s = rem % 400;
            o_heT[j] = (bf16_t)he[(s*BS + b)*DIM + d]; continue; }     j -= S3;
        if (j < S4) { o_wae[j] = (bf16_t)Wae[j]; continue; }           j -= S4;
        if (j < S5) { o_wih[j] = (bf16_t)Wih[j]; continue; }           j -= S5;
        if (j < S6) { long n = j>>8, k = j&255; o_wprojT[j] = (bf16_t)Wproj[k*768 + n]; continue; } j -= S6;
        { long r = j>>8, k = j&255; o_embA[j] = (bf16_t)Wemb[(long)inputs[r]*DIM + k]; }
    }
}

// ---------------- generic bf16 MFMA GEMM tile, 128x128, BK=32 (device body) ----
// C[M,N] = A[M,K] @ B[N,K]^T  (row-major, K-contiguous). A32!=null: A read fp32.
// mode 0: fp32 out + bias0 + bias1
// mode 1: bf16 out, tanh
// mode 2: bf16 out
// mode 3: exp(v+bias0), pad col -> 0, accumulate row sums into rsum (atomics)
// mode 4: fp32 out + bias0 + bias1, written TRANSPOSED-per-gate for the LSTM:
//         out[row*1024 + (col&255)*4 + (col>>8)]   (N must be 1024)
__device__ __forceinline__ void gemm_tile(
    const int tid, bf16_t* As, bf16_t* Bs,
    const bf16_t* __restrict__ A, const float* __restrict__ A32,
    const bf16_t* __restrict__ B,
    const int tileIdx, const int N, const int K, const int Ntiles, const int mode,
    float* __restrict__ outF, bf16_t* __restrict__ outB,
    const float* __restrict__ bias0, const float* __restrict__ bias1,
    const int* __restrict__ padp, float* __restrict__ rsum)
{
    const int mt   = tileIdx / Ntiles, nt = tileIdx % Ntiles;
    const int m0   = mt*128, n0 = nt*128;
    const int lane = tid & 63, wave = tid >> 6;
    const int wm   = wave >> 1, wn = wave & 1;
    const int quad = lane >> 4, l16 = lane & 15;

    v4f acc[4][4];
#pragma unroll
    for (int i=0;i<4;i++)
#pragma unroll
        for (int j=0;j<4;j++) acc[i][j] = (v4f){0.f,0.f,0.f,0.f};

    const int srow = tid >> 1, shalf = tid & 1;       // staging: 2 threads/row
    const bf16_t* Ag   = A   ? A   + (size_t)(m0+srow)*K + shalf*16 : nullptr;
    const float*  Ag32 = A32 ? A32 + (size_t)(m0+srow)*K + shalf*16 : nullptr;
    const bf16_t* Bg = B + (size_t)(n0+srow)*K + shalf*16;
    bf16_t* AsW = &As[srow*40 + shalf*16];
    bf16_t* BsW = &Bs[srow*40 + shalf*16];

    for (int kc = 0; kc < K; kc += 32) {
        __syncthreads();
        uint4 b0 = *(const uint4*)(Bg + kc);
        uint4 b1 = *(const uint4*)(Bg + kc + 8);
        if (A32) {
            float4 f0 = *(const float4*)(Ag32 + kc);
            float4 f1 = *(const float4*)(Ag32 + kc + 4);
            float4 f2 = *(const float4*)(Ag32 + kc + 8);
            float4 f3 = *(const float4*)(Ag32 + kc + 12);
            v8bf u0, u1;
            u0[0]=(bf16_t)f0.x; u0[1]=(bf16_t)f0.y; u0[2]=(bf16_t)f0.z; u0[3]=(bf16_t)f0.w;
            u0[4]=(bf16_t)f1.x; u0[5]=(bf16_t)f1.y; u0[6]=(bf16_t)f1.z; u0[7]=(bf16_t)f1.w;
            u1[0]=(bf16_t)f2.x; u1[1]=(bf16_t)f2.y; u1[2]=(bf16_t)f2.z; u1[3]=(bf16_t)f2.w;
            u1[4]=(bf16_t)f3.x; u1[5]=(bf16_t)f3.y; u1[6]=(bf16_t)f3.z; u1[7]=(bf16_t)f3.w;
            *(v8bf*)AsW = u0; *(v8bf*)(AsW+8) = u1;
        } else {
            uint4 a0 = *(const uint4*)(Ag + kc);
            uint4 a1 = *(const uint4*)(Ag + kc + 8);
            *(uint4*)AsW = a0; *(uint4*)(AsW+8) = a1;
        }
        *(uint4*)BsW = b0; *(uint4*)(BsW+8) = b1;
        __syncthreads();
        v8bf af[4], bb[4];
#pragma unroll
        for (int i=0;i<4;i++) {
            af[i] = *(const v8bf*)&As[(wm*64 + i*16 + l16)*40 + quad*8];
            bb[i] = *(const v8bf*)&Bs[(wn*64 + i*16 + l16)*40 + quad*8];
        }
#pragma unroll
        for (int i=0;i<4;i++)
#pragma unroll
            for (int j=0;j<4;j++)
                acc[i][j] = __builtin_amdgcn_mfma_f32_16x16x32_bf16(af[i], bb[j], acc[i][j], 0,0,0);
    }

    const int pad = padp ? *padp : -1;
    float* rs = (float*)As;          // LDS reuse for mode-3 row partial sums
    if (mode == 3) {
        __syncthreads();             // everyone past last As read
        if (tid < 128) rs[tid] = 0.f;
        __syncthreads();
    }
#pragma unroll
    for (int i=0;i<4;i++) {
        float rloc[4] = {0.f,0.f,0.f,0.f};
#pragma unroll
        for (int j=0;j<4;j++) {
#pragma unroll
            for (int r=0;r<4;r++) {
                const int gr = m0 + wm*64 + i*16 + quad*4 + r;   // C/D row = quad*4+reg
                const int gc = n0 + wn*64 + j*16 + l16;          // C/D col = lane&15
                const float v = acc[i][j][r];
                if (mode == 0)      outF[(size_t)gr*N + gc] = v + bias0[gc] + bias1[gc];
                else if (mode == 1) outB[(size_t)gr*N + gc] = (bf16_t)fast_tanh(v);
                else if (mode == 2) outB[(size_t)gr*N + gc] = (bf16_t)v;
                else if (mode == 4) outF[(size_t)gr*N + (gc & 255)*4 + (gc >> 8)] = v + bias0[gc] + bias1[gc];
                else {
                    float ex = (gc == pad) ? 0.f : __expf(v + bias0[gc]);
                    outF[(size_t)gr*N + gc] = ex;
                    rloc[r] += ex;
                }
            }
        }
        if (mode == 3) {
#pragma unroll
            for (int r=0;r<4;r++)
                atomicAdd(&rs[wm*64 + i*16 + quad*4 + r], rloc[r]);
        }
    }
    if (mode == 3) {
        __syncthreads();
        if (tid < 128) atomicAdd(&rsum[m0 + tid], rs[tid]);
    }
}

// standalone 256-thread GEMM wrapper (used for xg mode-4 and the big mode-3)
__global__ __launch_bounds__(256) void k_gemm(
    const bf16_t* __restrict__ A, const float* __restrict__ A32,
    const bf16_t* __restrict__ B,
    int M, int N, int K, int Ntiles, int mode,
    float* outF, bf16_t* outB,
    const float* __restrict__ bias0, const float* __restrict__ bias1,
    const int* __restrict__ padp, float* __restrict__ rsum)
{
    (void)M;
    __shared__ bf16_t As[128*40];
    __shared__ bf16_t Bs[128*40];
    gemm_tile(threadIdx.x, As, Bs, A, A32, B, blockIdx.x, N, K, Ntiles, mode,
              outF, outB, bias0, bias1, padp, rsum);
}

// ---------------- sequential LSTM chain body: ONE block, weight-resident -------
// 512 threads = 8 waves (2/SIMD). Wave w owns d-slice [w*32,w*32+32).
// Gate rows g*256+d: g=0,1 in registers (128 VGPR, likely AGPR-held),
// g=2 preloaded per step into ws[2][8] (ALL 16 L2 loads issued upfront, ONE
// latency — per-kc streaming was a measured -87us regression in round 1),
// g=3 in LDS (128 KB). xg pre-transposed to [row][d][gate]: epilogue issues
// 8 coalesced float4 loads upfront (round 0 used 32 scalar strided loads).
__device__ void lstm_body(char* sh,
    const bf16_t* __restrict__ Whh, const float* __restrict__ xgT,
    const float* __restrict__ h0, const float* __restrict__ c0,
    float* __restrict__ hallF, bf16_t* __restrict__ hallB)
{
    bf16_t* wlds = (bf16_t*)sh;              // 131072 B: gate-3 tiles
    bf16_t* hhi  = (bf16_t*)(sh + 131072);   // [16][264]
    bf16_t* hlo  = (bf16_t*)(sh + 139520);   // [16][264]

    const int tid = threadIdx.x;
    const int w = tid >> 6, lane = tid & 63;
    const int l16 = lane & 15, quad = lane >> 4;

    // preload gate-3 weights into LDS (conflict-free layout)
    for (int idx = tid; idx < 8192; idx += 512) {
        int tl = idx >> 9, u = idx & 511;
        int kc = u >> 6, r16 = (u >> 2) & 15, q = u & 3;
        int grow = 768 + (tl >> 1)*32 + (tl & 1)*16 + r16;
        *(uint4*)&wlds[idx*8] = *(const uint4*)&Whh[(size_t)grow*DIM + kc*32 + q*8];
    }
    // preload gate-0/1 weights into registers: wreg[g*2+hf][kc]
    v8bf wreg[4][8];
#pragma unroll
    for (int g = 0; g < 2; ++g)
#pragma unroll
      for (int hf = 0; hf < 2; ++hf)
#pragma unroll
        for (int kc = 0; kc < 8; ++kc)
            wreg[g*2+hf][kc] = *(const v8bf*)&Whh[(size_t)(g*256 + w*32 + hf*16 + l16)*DIM + kc*32 + quad*8];

    for (int i = tid; i < 4096; i += 512) {
        int b = i >> 8, d = i & 255;
        float v = h0[b*DIM + d];
        bf16_t hi = (bf16_t)v;
        hhi[b*264+d] = hi; hlo[b*264+d] = (bf16_t)(v - (float)hi);
    }
    float c[2][4];
#pragma unroll
    for (int hf = 0; hf < 2; ++hf)
#pragma unroll
      for (int r = 0; r < 4; ++r)
        c[hf][r] = c0[(quad*4 + r)*DIM + w*32 + hf*16 + l16];
    __syncthreads();

    const bf16_t* g2base = Whh + (size_t)(512 + w*32 + l16)*DIM + quad*8;
    for (int step = 0; step < TGT; ++step) {
        // gate-2 weight preload: ALL 16 loads issued before the MFMA loop
        // (loop-invariant addresses, L2-hot -> single overlapped latency)
        v8bf ws[2][8];
#pragma unroll
        for (int hf = 0; hf < 2; ++hf)
#pragma unroll
          for (int kc = 0; kc < 8; ++kc)
            ws[hf][kc] = *(const v8bf*)(g2base + (size_t)hf*16*DIM + kc*32);

        v4f acc[4][2];
#pragma unroll
        for (int g = 0; g < 4; ++g)
#pragma unroll
          for (int hf = 0; hf < 2; ++hf) acc[g][hf] = (v4f){0.f,0.f,0.f,0.f};

#pragma unroll
        for (int kc = 0; kc < 8; ++kc) {
            v8bf ahi = *(const v8bf*)&hhi[l16*264 + kc*32 + quad*8];
            v8bf alo = *(const v8bf*)&hlo[l16*264 + kc*32 + quad*8];
#pragma unroll
            for (int g = 0; g < 2; ++g)
#pragma unroll
              for (int hf = 0; hf < 2; ++hf) {
                acc[g][hf] = __builtin_amdgcn_mfma_f32_16x16x32_bf16(ahi, wreg[g*2+hf][kc], acc[g][hf], 0,0,0);
                acc[g][hf] = __builtin_amdgcn_mfma_f32_16x16x32_bf16(alo, wreg[g*2+hf][kc], acc[g][hf], 0,0,0);
              }
#pragma unroll
            for (int hf = 0; hf < 2; ++hf) {
                acc[2][hf] = __builtin_amdgcn_mfma_f32_16x16x32_bf16(ahi, ws[hf][kc], acc[2][hf], 0,0,0);
                acc[2][hf] = __builtin_amdgcn_mfma_f32_16x16x32_bf16(alo, ws[hf][kc], acc[2][hf], 0,0,0);
                v8bf bl = *(const v8bf*)&wlds[(((w*2+hf)*8 + kc)*16 + l16)*32 + quad*8];
                acc[3][hf] = __builtin_amdgcn_mfma_f32_16x16x32_bf16(ahi, bl, acc[3][hf], 0,0,0);
                acc[3][hf] = __builtin_amdgcn_mfma_f32_16x16x32_bf16(alo, bl, acc[3][hf], 0,0,0);
            }
        }
        __syncthreads();   // all reads of old h complete
        // epilogue: issue all 8 xg float4 loads upfront, then compute
        float4 xv[2][4];
#pragma unroll
        for (int hf = 0; hf < 2; ++hf) {
            const int d = w*32 + hf*16 + l16;
#pragma unroll
            for (int r = 0; r < 4; ++r) {
                const int b = quad*4 + r;
                xv[hf][r] = *(const float4*)(xgT + ((size_t)(step*BS + b)*DIM + d)*4);
            }
        }
#pragma unroll
        for (int hf = 0; hf < 2; ++hf) {
            const int d = w*32 + hf*16 + l16;
#pragma unroll
            for (int r = 0; r < 4; ++r) {
                const int b = quad*4 + r;
                const float gi = acc[0][hf][r] + xv[hf][r].x;
                const float gf = acc[1][hf][r] + xv[hf][r].y;
                const float gg = acc[2][hf][r] + xv[hf][r].z;
                const float go = acc[3][hf][r] + xv[hf][r].w;
                const float si = 1.f/(1.f+__expf(-gi));
                const float sf = 1.f/(1.f+__expf(-gf));
                const float so = 1.f/(1.f+__expf(-go));
                const float cn = sf*c[hf][r] + si*fast_tanh(gg);
                const float hn = so*fast_tanh(cn);
                c[hf][r] = cn;
                const bf16_t hi = (bf16_t)hn;
                hhi[b*264+d] = hi; hlo[b*264+d] = (bf16_t)(hn - (float)hi);
                hallF[(size_t)(step*BS + b)*DIM + d] = hn;
                hallB[(size_t)(step*BS + b)*DIM + d] = hi;
            }
        }
        __syncthreads();
    }
}

// ---------------- fused: block 0 = LSTM chain, other blocks = independent GEMMs -
// Blocks 1..750: W_out = tanh(W_emb @ W_proj) tiles (2 tiles per block, one per
// 256-thread half). Blocks 751..800: ke = h_e @ W_ae^T tiles. These are fully
// independent of the LSTM and run in its shadow (they drain in ~30us).
__global__ __launch_bounds__(512, 2) void k_fused(
    const bf16_t* __restrict__ Whh, const float* __restrict__ xgT,
    const float* __restrict__ h0, const float* __restrict__ c0,
    float* __restrict__ hallF, bf16_t* __restrict__ hallB,
    const float* __restrict__ Wemb, const bf16_t* __restrict__ wprojT, bf16_t* __restrict__ woutB,
    const bf16_t* __restrict__ heA, const bf16_t* __restrict__ waeB, bf16_t* __restrict__ keB)
{
    __shared__ __align__(16) char sh[147968];
    const int bid = blockIdx.x;
    if (bid == 0) {
        lstm_body(sh, Whh, xgT, h0, c0, hallF, hallB);
        return;
    }
    const int half = threadIdx.x >> 8;        // wave 0-3 vs 4-7: two independent tiles
    const int tid  = threadIdx.x & 255;
    bf16_t* As = (bf16_t*)(sh + half*20480);
    bf16_t* Bs = (bf16_t*)(sh + half*20480 + 10240);
    if (bid <= 750) {      // W_out: M=32000, N=768, K=256, Ntiles=6 -> 1500 tiles
        const int tile = (bid - 1)*2 + half;
        gemm_tile(tid, As, Bs, nullptr, Wemb, wprojT, tile, 768, 256, 6, 1,
                  nullptr, woutB, nullptr, nullptr, nullptr, nullptr);
    } else {               // ke: M=6400, N=256, K=256, Ntiles=2 -> 100 tiles
        const int tile = (bid - 751)*2 + half;
        gemm_tile(tid, As, Bs, heA, nullptr, waeB, tile, 256, 256, 2, 2,
                  nullptr, keB, nullptr, nullptr, nullptr, nullptr);
    }
}

// ---------------- expE[t,b,s] = exp(ke[s,b,:] . h[t,b,:]) (device body) --------
__device__ __forceinline__ void escore_body(const int blk, const int tid, float* hS,
    const bf16_t* __restrict__ ke, const float* __restrict__ hallF, float* __restrict__ expE)
{
    const int t = blk >> 4, b = blk & 15;
    hS[tid] = hallF[(size_t)(t*BS + b)*DIM + tid];
    __syncthreads();
    for (int s = tid; s < SRC; s += 256) {
        const v8bf* kp = (const v8bf*)(ke + ((size_t)s*BS + b)*DIM);
        float e = 0.f;
#pragma unroll 8
        for (int m=0;m<32;m++) {
            v8bf kv = kp[m];
#pragma unroll
            for (int i=0;i<8;i++) e += (float)kv[i]*hS[m*8+i];
        }
        expE[((size_t)t*BS + b)*SRC + s] = __expf(e);
    }
}

// fused escore + qd GEMM (qd = h_all @ W_attn_dec, 6 tiles) — both depend only on
// the LSTM outputs, so they share one launch.
__global__ __launch_bounds__(256) void k_esq(
    const bf16_t* __restrict__ ke, const float* __restrict__ hallF, float* __restrict__ expE,
    const bf16_t* __restrict__ hallB, const bf16_t* __restrict__ wadT, bf16_t* __restrict__ qdG)
{
    __shared__ __align__(16) char shb[20480];
    if (blockIdx.x < NROW) {
        escore_body(blockIdx.x, threadIdx.x, (float*)shb, ke, hallF, expE);
        return;
    }
    gemm_tile(threadIdx.x, (bf16_t*)shb, (bf16_t*)(shb + 10240), hallB, nullptr, wadT,
              blockIdx.x - NROW, 256, 256, 2, 2, nullptr, qdG, nullptr, nullptr, nullptr, nullptr);
}

// ---------------- per-(t,b) attention tail ----------------
__global__ __launch_bounds__(256) void k_attn2(
    const float* __restrict__ expE, const bf16_t* __restrict__ heT,
    const float* __restrict__ hallF, const bf16_t* __restrict__ qdG,
    const float* __restrict__ wu, const float* __restrict__ bu,
    bf16_t* __restrict__ feat, float* __restrict__ Ae, float* __restrict__ ps)
{
    const int t = blockIdx.x >> 4, b = blockIdx.x & 15;
    const int tid = threadIdx.x;
    __shared__ float hS[DIM], qdS[DIM], eeS[SRC], adS[TGT];
    __shared__ float red[4], misc[2];

    hS[tid]  = hallF[(size_t)(t*BS + b)*DIM + tid];
    qdS[tid] = (float)qdG[(size_t)(t*BS + b)*DIM + tid];
    __syncthreads();

    for (int s = tid; s < SRC; s += 256) {
        float prev = 0.f;
        for (int tp = 0; tp < t; ++tp) prev += expE[((size_t)tp*BS + b)*SRC + s];
        float my = expE[((size_t)t*BS + b)*SRC + s];
        eeS[s] = (t == 0) ? my : my / prev;
    }
    __syncthreads();
    {   // esum
        float pa = 0.f;
        for (int s = tid; s < SRC; s += 256) pa += eeS[s];
#pragma unroll
        for (int o=32;o>0;o>>=1) pa += __shfl_down(pa, o);
        if ((tid & 63) == 0) red[tid>>6] = pa;
        __syncthreads();
        if (tid == 0) misc[0] = 1.f/(red[0]+red[1]+red[2]+red[3]);
        __syncthreads();
    }
    const float inv_es = misc[0];
    for (int s = tid; s < SRC; s += 256)
        Ae[((size_t)t*BS + b)*SRC + s] = eeS[s] * inv_es;

    float ce;
    {
        const v8bf* hp = (const v8bf*)(heT + ((size_t)b*DIM + tid)*SRC);
        float acc = 0.f;
#pragma unroll 10
        for (int m=0;m<50;m++) {
            v8bf hv = hp[m];
#pragma unroll
            for (int i=0;i<8;i++) acc += (float)hv[i]*eeS[m*8+i];
        }
        ce = acc * inv_es;
    }

    {
        const int wv = tid >> 6, ln = tid & 63;
        for (int tau = wv; tau <= t; tau += 4) {
            float4 a = *(const float4*)(hallF + ((size_t)(tau*BS + b))*DIM + ln*4);
            float e = a.x*qdS[ln*4] + a.y*qdS[ln*4+1] + a.z*qdS[ln*4+2] + a.w*qdS[ln*4+3];
#pragma unroll
            for (int o=32;o>0;o>>=1) e += __shfl_down(e, o);
            if (ln == 0) adS[tau] = __expf(e);
        }
    }
    __syncthreads();
    if (tid < 64) {
        float v = (tid <= t) ? adS[tid] : 0.f;
#pragma unroll
        for (int o=32;o>0;o>>=1) v += __shfl_down(v, o);
        if (tid == 0) misc[1] = 1.f/v;
    }
    __syncthreads();
    float cd = 0.f;
    for (int tau = 0; tau <= t; ++tau)
        cd += adS[tau] * hallF[((size_t)(tau*BS + b))*DIM + tid];
    cd *= misc[1];
    if (t == 0) cd = 0.f;

    const float hd = hS[tid];
    const size_t fr = ((size_t)t*BS + b)*768;
    feat[fr + tid]       = (bf16_t)hd;
    feat[fr + 256 + tid] = (bf16_t)ce;
    feat[fr + 512 + tid] = (bf16_t)cd;
    float pw = hd*wu[tid] + ce*wu[256 + tid] + cd*wu[512 + tid];
#pragma unroll
    for (int o=32;o>0;o>>=1) pw += __shfl_down(pw, o);
    if ((tid & 63) == 0) red[tid>>6] = pw;
    __syncthreads();
    if (tid == 0) {
        float s = red[0]+red[1]+red[2]+red[3];
        ps[t*BS + b] = 1.f/(1.f+__expf(-(s + bu[0])));
    }
}

// ---------------- final: scale row by ps[r]/rsum[r], then copy-scatter ---------
// One block per output row: the 128 KB row is L2-hot for the scatter, and one
// launch replaces the old k_norm + k_copy pair.
__global__ __launch_bounds__(256) void k_final(
    float* __restrict__ out, const float* __restrict__ rsum,
    const float* __restrict__ ps, const int* __restrict__ src,
    const float* __restrict__ Ae)
{
    const int r = blockIdx.x;        // r = t*BS + b
    const int b = r & (BS-1);
    const float p  = ps[r];
    const float sc = p / rsum[r];
    float4* o4 = (float4*)(out + (size_t)r*VOCABN);
    for (int i = threadIdx.x; i < VOCABN/4; i += 256) {
        float4 v = o4[i];
        v.x*=sc; v.y*=sc; v.z*=sc; v.w*=sc;
        o4[i] = v;
    }
    __syncthreads();   // row fully scaled before scatter into it
    for (int s = threadIdx.x; s < SRC; s += 256) {
        const int v = src[s*BS + b];
        atomicAdd(&out[(size_t)r*VOCABN + v], Ae[(size_t)r*SRC + s] * p);
    }
}

// ---------------- workspace layout (bytes, 16B-aligned) ----------------
#define O_WHH    0u
#define O_WADT   524288u
#define O_HEBF   655360u
#define O_HET    3932160u
#define O_KE     7208960u
#define O_WAE    10485760u
#define O_WPROJT 10616832u
#define O_WIH    11010048u
#define O_EMBA   11534336u
#define O_WOUT   11730944u
#define O_XG     60882944u
#define O_HALLF  62455808u
#define O_HALLB  62849024u
#define O_QD     63045632u
#define O_EXPE   63242240u
#define O_FEAT   63856640u
#define O_AE     64446464u
#define O_PS     65060864u
#define O_SCALE  65062400u
#define O_RSUM   65063936u   // 1536 B, zeroed each call

extern "C" void kernel_launch(void* const* d_in, const int* in_sizes, int n_in,
                              void* d_out, int out_size, void* d_ws, size_t ws_size,
                              hipStream_t stream)
{
    const int*   inputs = (const int*)  d_in[0];
    const int*   src    = (const int*)  d_in[1];
    const float* h_e    = (const float*)d_in[2];
    const float* h0     = (const float*)d_in[3];
    const float* c0     = (const float*)d_in[4];
    const float* W_emb  = (const float*)d_in[5];
    const float* W_ih   = (const float*)d_in[6];
    const float* b_ih   = (const float*)d_in[7];
    const float* W_hh   = (const float*)d_in[8];
    const float* b_hh   = (const float*)d_in[9];
    const float* W_ae   = (const float*)d_in[10];
    const float* W_ad   = (const float*)d_in[11];
    const float* W_proj = (const float*)d_in[12];
    const float* W_u    = (const float*)d_in[13];
    const float* b_u    = (const float*)d_in[14];
    const float* b_out  = (const float*)d_in[15];
    const int*   pad_id = (const int*)  d_in[16];

    char* w = (char*)d_ws;
    bf16_t* whh_bf  = (bf16_t*)(w + O_WHH);
    bf16_t* wadT_bf = (bf16_t*)(w + O_WADT);
    bf16_t* he_bf   = (bf16_t*)(w + O_HEBF);
    bf16_t* heT_bf  = (bf16_t*)(w + O_HET);
    bf16_t* ke_bf   = (bf16_t*)(w + O_KE);
    bf16_t* wae_bf  = (bf16_t*)(w + O_WAE);
    bf16_t* wprojT  = (bf16_t*)(w + O_WPROJT);
    bf16_t* wih_bf  = (bf16_t*)(w + O_WIH);
    bf16_t* embA_bf = (bf16_t*)(w + O_EMBA);
    bf16_t* wout_bf = (bf16_t*)(w + O_WOUT);
    float*  xg      = (float*) (w + O_XG);      // holds xgT: [row][d][gate]
    float*  hallF   = (float*) (w + O_HALLF);
    bf16_t* hallB   = (bf16_t*)(w + O_HALLB);
    bf16_t* qdG     = (bf16_t*)(w + O_QD);
    float*  expE    = (float*) (w + O_EXPE);
    bf16_t* feat_bf = (bf16_t*)(w + O_FEAT);
    float*  Ae      = (float*) (w + O_AE);
    float*  ps      = (float*) (w + O_PS);
    float*  rsum    = (float*) (w + O_RSUM);
    float*  out     = (float*)d_out;

    k_prep<<<1024, 256, 0, stream>>>(W_hh, W_ad, h_e, W_emb, W_proj, W_ae, W_ih, inputs,
                                     whh_bf, wadT_bf, he_bf, heT_bf,
                                     wae_bf, wih_bf, wprojT, embA_bf);
    hipMemsetAsync(w + O_RSUM, 0, 1536, stream);
    // xgT = (embA @ W_ih^T + b_ih + b_hh) transposed-per-gate  (M=384, N=1024, K=256)
    k_gemm<<<24, 256, 0, stream>>>(embA_bf, nullptr, wih_bf, NROW, 1024, 256, 8, 4,
                                   xg, nullptr, b_ih, b_hh, nullptr, nullptr);
    // fused: sequential LSTM (block 0) + W_out GEMM (blocks 1-750) + ke GEMM (751-800)
    k_fused<<<801, 512, 0, stream>>>(whh_bf, xg, h0, c0, hallF, hallB,
                                     W_emb, wprojT, wout_bf,
                                     he_bf, wae_bf, ke_bf);
    // fused: escore (blocks 0-383) + qd GEMM (blocks 384-389)
    k_esq<<<NROW + 6, 256, 0, stream>>>(ke_bf, hallF, expE, hallB, wadT_bf, qdG);
    k_attn2<<<NROW, 256, 0, stream>>>(expE, heT_bf, hallF, qdG, W_u, b_u,
                                      feat_bf, Ae, ps);
    // exp(logits + b_out), pad -> 0, + fused row sums  (M=384, N=32000, K=768)
    k_gemm<<<750, 256, 0, stream>>>(feat_bf, nullptr, wout_bf, NROW, VOCABN, 768, 250, 3,
                                    out, nullptr, b_out, nullptr, pad_id, rsum);
    // scale + copy-scatter, one block per row
    k_final<<<NROW, 256, 0, stream>>>(out, rsum, ps, src, Ae);
}

// Round 3
// 519.552 us; speedup vs baseline: 1.0543x; 1.0235x over previous
//
#include <hip/hip_runtime.h>
#include <cstdint>
#include <cstddef>

// ---------------- problem constants ----------------
#define TGT   24
#define BS    16
#define SRC   400
#define VOCABN 32000
#define DIM   256
#define NROW  (TGT*BS)   // 384

typedef __bf16 bf16_t;
typedef __bf16 v8bf __attribute__((ext_vector_type(8)));
typedef float  v4f  __attribute__((ext_vector_type(4)));

__device__ __forceinline__ float fast_tanh(float x) {
    // monotone, no NaN for large |x|: e->0 => -1, e->inf => +1
    float e = __expf(2.f*x);
    return 1.f - 2.f/(e + 1.f);
}

// ---------------- prep: dtype conversions / transposes / gather ----------------
__global__ void k_prep(const float* __restrict__ Whh, const float* __restrict__ Wad,
                       const float* __restrict__ he,  const float* __restrict__ Wemb,
                       const float* __restrict__ Wproj, const float* __restrict__ Wae,
                       const float* __restrict__ Wih, const int* __restrict__ inputs,
                       bf16_t* o_whh, bf16_t* o_wadT, bf16_t* o_he, bf16_t* o_heT,
                       bf16_t* o_wae, bf16_t* o_wih, bf16_t* o_wprojT, bf16_t* o_embA)
{
    const long S0=262144, S1=65536, S2=1638400, S3=1638400, S4=65536, S5=262144, S6=196608, S7=98304;
    const long total = S0+S1+S2+S3+S4+S5+S6+S7;
    for (long i = (long)blockIdx.x*blockDim.x + threadIdx.x; i < total;
         i += (long)gridDim.x*blockDim.x) {
        long j = i;
        if (j < S0) { o_whh[j] = (bf16_t)Whh[j]; continue; }           j -= S0;
        if (j < S1) { long n = j>>8, k = j&255; o_wadT[j] = (bf16_t)Wad[k*DIM + n]; continue; } j -= S1;
        if (j < S2) { o_he[j] = (bf16_t)he[j]; continue; }             j -= S2;
        if (j < S3) { // heT[b][d][s] = he[(s*BS+b)*DIM+d]
            long b = j / 102400, rem = j % 102400, d = rem / 400, s = rem % 400;
            o_heT[j] = (bf16_t)he[(s*BS + b)*DIM + d]; continue; }     j -= S3;
        if (j < S4) { o_wae[j] = (bf16_t)Wae[j]; continue; }           j -= S4;
        if (j < S5) { o_wih[j] = (bf16_t)Wih[j]; continue; }           j -= S5;
        if (j < S6) { long n = j>>8, k = j&255; o_wprojT[j] = (bf16_t)Wproj[k*768 + n]; continue; } j -= S6;
        { long r = j>>8, k = j&255; o_embA[j] = (bf16_t)Wemb[(long)inputs[r]*DIM + k]; }
    }
}

// ---------------- generic bf16 MFMA GEMM tile, 128x128, BK=32 (device body) ----
// C[M,N] = A[M,K] @ B[N,K]^T  (row-major, K-contiguous). A32!=null: A read fp32.
// mode 0: fp32 out + bias0 + bias1
// mode 1: bf16 out, tanh
// mode 2: bf16 out
// mode 3: exp(v+bias0), pad col -> 0, accumulate row sums into rsum (atomics)
// mode 4: fp32 out + bias0 + bias1, written TRANSPOSED-per-gate for the LSTM:
//         out[row*1024 + (col&255)*4 + (col>>8)]   (N must be 1024)
__device__ __forceinline__ void gemm_tile(
    const int tid, bf16_t* As, bf16_t* Bs,
    const bf16_t* __restrict__ A, const float* __restrict__ A32,
    const bf16_t* __restrict__ B,
    const int tileIdx, const int N, const int K, const int Ntiles, const int mode,
    float* __restrict__ outF, bf16_t* __restrict__ outB,
    const float* __restrict__ bias0, const float* __restrict__ bias1,
    const int* __restrict__ padp, float* __restrict__ rsum)
{
    const int mt   = tileIdx / Ntiles, nt = tileIdx % Ntiles;
    const int m0   = mt*128, n0 = nt*128;
    const int lane = tid & 63, wave = tid >> 6;
    const int wm   = wave >> 1, wn = wave & 1;
    const int quad = lane >> 4, l16 = lane & 15;

    v4f acc[4][4];
#pragma unroll
    for (int i=0;i<4;i++)
#pragma unroll
        for (int j=0;j<4;j++) acc[i][j] = (v4f){0.f,0.f,0.f,0.f};

    const int srow = tid >> 1, shalf = tid & 1;       // staging: 2 threads/row
    const bf16_t* Ag   = A   ? A   + (size_t)(m0+srow)*K + shalf*16 : nullptr;
    const float*  Ag32 = A32 ? A32 + (size_t)(m0+srow)*K + shalf*16 : nullptr;
    const bf16_t* Bg = B + (size_t)(n0+srow)*K + shalf*16;
    bf16_t* AsW = &As[srow*40 + shalf*16];
    bf16_t* BsW = &Bs[srow*40 + shalf*16];

    for (int kc = 0; kc < K; kc += 32) {
        __syncthreads();
        uint4 b0 = *(const uint4*)(Bg + kc);
        uint4 b1 = *(const uint4*)(Bg + kc + 8);
        if (A32) {
            float4 f0 = *(const float4*)(Ag32 + kc);
            float4 f1 = *(const float4*)(Ag32 + kc + 4);
            float4 f2 = *(const float4*)(Ag32 + kc + 8);
            float4 f3 = *(const float4*)(Ag32 + kc + 12);
            v8bf u0, u1;
            u0[0]=(bf16_t)f0.x; u0[1]=(bf16_t)f0.y; u0[2]=(bf16_t)f0.z; u0[3]=(bf16_t)f0.w;
            u0[4]=(bf16_t)f1.x; u0[5]=(bf16_t)f1.y; u0[6]=(bf16_t)f1.z; u0[7]=(bf16_t)f1.w;
            u1[0]=(bf16_t)f2.x; u1[1]=(bf16_t)f2.y; u1[2]=(bf16_t)f2.z; u1[3]=(bf16_t)f2.w;
            u1[4]=(bf16_t)f3.x; u1[5]=(bf16_t)f3.y; u1[6]=(bf16_t)f3.z; u1[7]=(bf16_t)f3.w;
            *(v8bf*)AsW = u0; *(v8bf*)(AsW+8) = u1;
        } else {
            uint4 a0 = *(const uint4*)(Ag + kc);
            uint4 a1 = *(const uint4*)(Ag + kc + 8);
            *(uint4*)AsW = a0; *(uint4*)(AsW+8) = a1;
        }
        *(uint4*)BsW = b0; *(uint4*)(BsW+8) = b1;
        __syncthreads();
        v8bf af[4], bb[4];
#pragma unroll
        for (int i=0;i<4;i++) {
            af[i] = *(const v8bf*)&As[(wm*64 + i*16 + l16)*40 + quad*8];
            bb[i] = *(const v8bf*)&Bs[(wn*64 + i*16 + l16)*40 + quad*8];
        }
#pragma unroll
        for (int i=0;i<4;i++)
#pragma unroll
            for (int j=0;j<4;j++)
                acc[i][j] = __builtin_amdgcn_mfma_f32_16x16x32_bf16(af[i], bb[j], acc[i][j], 0,0,0);
    }

    const int pad = padp ? *padp : -1;
    float* rs = (float*)As;          // LDS reuse for mode-3 row partial sums
    if (mode == 3) {
        __syncthreads();             // everyone past last As read
        if (tid < 128) rs[tid] = 0.f;
        __syncthreads();
    }
#pragma unroll
    for (int i=0;i<4;i++) {
        float rloc[4] = {0.f,0.f,0.f,0.f};
#pragma unroll
        for (int j=0;j<4;j++) {
#pragma unroll
            for (int r=0;r<4;r++) {
                const int gr = m0 + wm*64 + i*16 + quad*4 + r;   // C/D row = quad*4+reg
                const int gc = n0 + wn*64 + j*16 + l16;          // C/D col = lane&15
                const float v = acc[i][j][r];
                if (mode == 0)      outF[(size_t)gr*N + gc] = v + bias0[gc] + bias1[gc];
                else if (mode == 1) outB[(size_t)gr*N + gc] = (bf16_t)fast_tanh(v);
                else if (mode == 2) outB[(size_t)gr*N + gc] = (bf16_t)v;
                else if (mode == 4) outF[(size_t)gr*N + (gc & 255)*4 + (gc >> 8)] = v + bias0[gc] + bias1[gc];
                else {
                    float ex = (gc == pad) ? 0.f : __expf(v + bias0[gc]);
                    outF[(size_t)gr*N + gc] = ex;
                    rloc[r] += ex;
                }
            }
        }
        if (mode == 3) {
#pragma unroll
            for (int r=0;r<4;r++)
                atomicAdd(&rs[wm*64 + i*16 + quad*4 + r], rloc[r]);
        }
    }
    if (mode == 3) {
        __syncthreads();
        if (tid < 128) atomicAdd(&rsum[m0 + tid], rs[tid]);
    }
}

// standalone 256-thread GEMM wrapper (the big mode-3 logits GEMM)
__global__ __launch_bounds__(256) void k_gemm(
    const bf16_t* __restrict__ A, const float* __restrict__ A32,
    const bf16_t* __restrict__ B,
    int M, int N, int K, int Ntiles, int mode,
    float* outF, bf16_t* outB,
    const float* __restrict__ bias0, const float* __restrict__ bias1,
    const int* __restrict__ padp, float* __restrict__ rsum)
{
    (void)M;
    __shared__ bf16_t As[128*40];
    __shared__ bf16_t Bs[128*40];
    gemm_tile(threadIdx.x, As, Bs, A, A32, B, blockIdx.x, N, K, Ntiles, mode,
              outF, outB, bias0, bias1, padp, rsum);
}

// combined xg (mode 4, 24 tiles) + ke (mode 2, 100 tiles) — both depend only
// on k_prep, so they share one launch.
__global__ __launch_bounds__(256) void k_gemm2(
    const bf16_t* __restrict__ embA, const bf16_t* __restrict__ wih,
    float* __restrict__ xg, const float* __restrict__ b_ih, const float* __restrict__ b_hh,
    const bf16_t* __restrict__ heA, const bf16_t* __restrict__ waeB, bf16_t* __restrict__ keB)
{
    __shared__ bf16_t As[128*40];
    __shared__ bf16_t Bs[128*40];
    if (blockIdx.x < 24)
        gemm_tile(threadIdx.x, As, Bs, embA, nullptr, wih, blockIdx.x, 1024, 256, 8, 4,
                  xg, nullptr, b_ih, b_hh, nullptr, nullptr);
    else
        gemm_tile(threadIdx.x, As, Bs, heA, nullptr, waeB, blockIdx.x - 24, 256, 256, 2, 2,
                  nullptr, keB, nullptr, nullptr, nullptr, nullptr);
}

// ---------------- sequential LSTM chain: ONE block, weight-resident, STANDALONE -
// (Un-fused from the GEMM work: co-compiling this body in the same kernel as
// gemm_tile measured +85us (197->283, rounds 1-2) despite identical source and
// VGPR count — own kernel restores the measured-good codegen.)
// 512 threads = 8 waves (2/SIMD). Wave w owns d-slice [w*32,w*32+32).
// Gate rows g*256+d: g=0,1 in registers (AGPR-held), g=2 preloaded per step into
// ws[2][8] (all 16 L2 loads upfront, one latency), g=3 in LDS (128 KB).
// xg pre-transposed to [row][d][gate]: epilogue issues 8 coalesced float4 loads.
__global__ __launch_bounds__(512, 2) void k_lstm(
    const bf16_t* __restrict__ Whh, const float* __restrict__ xgT,
    const float* __restrict__ h0, const float* __restrict__ c0,
    float* __restrict__ hallF, bf16_t* __restrict__ hallB)
{
    __shared__ bf16_t wlds[65536];    // gate-3 tiles: [tile16][kc8][l16][quad*8]
    __shared__ bf16_t hhi[16][264];
    __shared__ bf16_t hlo[16][264];

    const int tid = threadIdx.x;
    const int w = tid >> 6, lane = tid & 63;
    const int l16 = lane & 15, quad = lane >> 4;

    // preload gate-3 weights into LDS (conflict-free layout)
    for (int idx = tid; idx < 8192; idx += 512) {
        int tl = idx >> 9, u = idx & 511;
        int kc = u >> 6, r16 = (u >> 2) & 15, q = u & 3;
        int grow = 768 + (tl >> 1)*32 + (tl & 1)*16 + r16;
        *(uint4*)&wlds[idx*8] = *(const uint4*)&Whh[(size_t)grow*DIM + kc*32 + q*8];
    }
    // preload gate-0/1 weights into registers: wreg[g*2+hf][kc]
    v8bf wreg[4][8];
#pragma unroll
    for (int g = 0; g < 2; ++g)
#pragma unroll
      for (int hf = 0; hf < 2; ++hf)
#pragma unroll
        for (int kc = 0; kc < 8; ++kc)
            wreg[g*2+hf][kc] = *(const v8bf*)&Whh[(size_t)(g*256 + w*32 + hf*16 + l16)*DIM + kc*32 + quad*8];

    for (int i = tid; i < 4096; i += 512) {
        int b = i >> 8, d = i & 255;
        float v = h0[b*DIM + d];
        bf16_t hi = (bf16_t)v;
        hhi[b][d] = hi; hlo[b][d] = (bf16_t)(v - (float)hi);
    }
    float c[2][4];
#pragma unroll
    for (int hf = 0; hf < 2; ++hf)
#pragma unroll
      for (int r = 0; r < 4; ++r)
        c[hf][r] = c0[(quad*4 + r)*DIM + w*32 + hf*16 + l16];
    __syncthreads();

    const bf16_t* g2base = Whh + (size_t)(512 + w*32 + l16)*DIM + quad*8;
    for (int step = 0; step < TGT; ++step) {
        // gate-2 weight preload: all 16 loads issued before the MFMA loop
        v8bf ws[2][8];
#pragma unroll
        for (int hf = 0; hf < 2; ++hf)
#pragma unroll
          for (int kc = 0; kc < 8; ++kc)
            ws[hf][kc] = *(const v8bf*)(g2base + (size_t)hf*16*DIM + kc*32);

        v4f acc[4][2];
#pragma unroll
        for (int g = 0; g < 4; ++g)
#pragma unroll
          for (int hf = 0; hf < 2; ++hf) acc[g][hf] = (v4f){0.f,0.f,0.f,0.f};

#pragma unroll
        for (int kc = 0; kc < 8; ++kc) {
            v8bf ahi = *(const v8bf*)&hhi[l16][kc*32 + quad*8];
            v8bf alo = *(const v8bf*)&hlo[l16][kc*32 + quad*8];
#pragma unroll
            for (int g = 0; g < 2; ++g)
#pragma unroll
              for (int hf = 0; hf < 2; ++hf) {
                acc[g][hf] = __builtin_amdgcn_mfma_f32_16x16x32_bf16(ahi, wreg[g*2+hf][kc], acc[g][hf], 0,0,0);
                acc[g][hf] = __builtin_amdgcn_mfma_f32_16x16x32_bf16(alo, wreg[g*2+hf][kc], acc[g][hf], 0,0,0);
              }
#pragma unroll
            for (int hf = 0; hf < 2; ++hf) {
                acc[2][hf] = __builtin_amdgcn_mfma_f32_16x16x32_bf16(ahi, ws[hf][kc], acc[2][hf], 0,0,0);
                acc[2][hf] = __builtin_amdgcn_mfma_f32_16x16x32_bf16(alo, ws[hf][kc], acc[2][hf], 0,0,0);
                v8bf bl = *(const v8bf*)&wlds[(((w*2+hf)*8 + kc)*16 + l16)*32 + quad*8];
                acc[3][hf] = __builtin_amdgcn_mfma_f32_16x16x32_bf16(ahi, bl, acc[3][hf], 0,0,0);
                acc[3][hf] = __builtin_amdgcn_mfma_f32_16x16x32_bf16(alo, bl, acc[3][hf], 0,0,0);
            }
        }
        __syncthreads();   // all reads of old h complete
        // epilogue: issue all 8 xg float4 loads upfront, then compute
        float4 xv[2][4];
#pragma unroll
        for (int hf = 0; hf < 2; ++hf) {
            const int d = w*32 + hf*16 + l16;
#pragma unroll
            for (int r = 0; r < 4; ++r) {
                const int b = quad*4 + r;
                xv[hf][r] = *(const float4*)(xgT + ((size_t)(step*BS + b)*DIM + d)*4);
            }
        }
#pragma unroll
        for (int hf = 0; hf < 2; ++hf) {
            const int d = w*32 + hf*16 + l16;
#pragma unroll
            for (int r = 0; r < 4; ++r) {
                const int b = quad*4 + r;
                const float gi = acc[0][hf][r] + xv[hf][r].x;
                const float gf = acc[1][hf][r] + xv[hf][r].y;
                const float gg = acc[2][hf][r] + xv[hf][r].z;
                const float go = acc[3][hf][r] + xv[hf][r].w;
                const float si = 1.f/(1.f+__expf(-gi));
                const float sf = 1.f/(1.f+__expf(-gf));
                const float so = 1.f/(1.f+__expf(-go));
                const float cn = sf*c[hf][r] + si*fast_tanh(gg);
                const float hn = so*fast_tanh(cn);
                c[hf][r] = cn;
                const bf16_t hi = (bf16_t)hn;
                hhi[b][d] = hi; hlo[b][d] = (bf16_t)(hn - (float)hi);
                hallF[(size_t)(step*BS + b)*DIM + d] = hn;
                hallB[(size_t)(step*BS + b)*DIM + d] = hi;
            }
        }
        __syncthreads();
    }
}

// ---------------- expE[t,b,s] = exp(ke[s,b,:] . h[t,b,:]) (device body) --------
__device__ __forceinline__ void escore_body(const int blk, const int tid, float* hS,
    const bf16_t* __restrict__ ke, const float* __restrict__ hallF, float* __restrict__ expE)
{
    const int t = blk >> 4, b = blk & 15;
    hS[tid] = hallF[(size_t)(t*BS + b)*DIM + tid];
    __syncthreads();
    for (int s = tid; s < SRC; s += 256) {
        const v8bf* kp = (const v8bf*)(ke + ((size_t)s*BS + b)*DIM);
        float e = 0.f;
#pragma unroll 8
        for (int m=0;m<32;m++) {
            v8bf kv = kp[m];
#pragma unroll
            for (int i=0;i<8;i++) e += (float)kv[i]*hS[m*8+i];
        }
        expE[((size_t)t*BS + b)*SRC + s] = __expf(e);
    }
}

// fused escore + qd GEMM (qd = h_all @ W_attn_dec, 6 tiles)
__global__ __launch_bounds__(256) void k_esq(
    const bf16_t* __restrict__ ke, const float* __restrict__ hallF, float* __restrict__ expE,
    const bf16_t* __restrict__ hallB, const bf16_t* __restrict__ wadT, bf16_t* __restrict__ qdG)
{
    __shared__ __align__(16) char shb[20480];
    if (blockIdx.x < NROW) {
        escore_body(blockIdx.x, threadIdx.x, (float*)shb, ke, hallF, expE);
        return;
    }
    gemm_tile(threadIdx.x, (bf16_t*)shb, (bf16_t*)(shb + 10240), hallB, nullptr, wadT,
              blockIdx.x - NROW, 256, 256, 2, 2, nullptr, qdG, nullptr, nullptr, nullptr, nullptr);
}

// ---------------- per-(t,b) attention tail (device body) ----------------
__device__ void attn_body(char* sh, const int blk, const int tid,
    const float* __restrict__ expE, const bf16_t* __restrict__ heT,
    const float* __restrict__ hallF, const bf16_t* __restrict__ qdG,
    const float* __restrict__ wu, const float* __restrict__ bu,
    bf16_t* __restrict__ feat, float* __restrict__ Ae, float* __restrict__ ps)
{
    float* hS   = (float*)sh;        // 256
    float* qdS  = hS + 256;          // 256
    float* eeS  = qdS + 256;         // 400
    float* adS  = eeS + 400;         // 24
    float* red  = adS + 24;          // 4
    float* misc = red + 4;           // 2
    const int t = blk >> 4, b = blk & 15;

    hS[tid]  = hallF[(size_t)(t*BS + b)*DIM + tid];
    qdS[tid] = (float)qdG[(size_t)(t*BS + b)*DIM + tid];
    __syncthreads();

    for (int s = tid; s < SRC; s += 256) {
        float prev = 0.f;
        for (int tp = 0; tp < t; ++tp) prev += expE[((size_t)tp*BS + b)*SRC + s];
        float my = expE[((size_t)t*BS + b)*SRC + s];
        eeS[s] = (t == 0) ? my : my / prev;
    }
    __syncthreads();
    {   // esum
        float pa = 0.f;
        for (int s = tid; s < SRC; s += 256) pa += eeS[s];
#pragma unroll
        for (int o=32;o>0;o>>=1) pa += __shfl_down(pa, o);
        if ((tid & 63) == 0) red[tid>>6] = pa;
        __syncthreads();
        if (tid == 0) misc[0] = 1.f/(red[0]+red[1]+red[2]+red[3]);
        __syncthreads();
    }
    const float inv_es = misc[0];
    for (int s = tid; s < SRC; s += 256)
        Ae[((size_t)t*BS + b)*SRC + s] = eeS[s] * inv_es;

    float ce;
    {
        const v8bf* hp = (const v8bf*)(heT + ((size_t)b*DIM + tid)*SRC);
        float acc = 0.f;
#pragma unroll 10
        for (int m=0;m<50;m++) {
            v8bf hv = hp[m];
#pragma unroll
            for (int i=0;i<8;i++) acc += (float)hv[i]*eeS[m*8+i];
        }
        ce = acc * inv_es;
    }

    {
        const int wv = tid >> 6, ln = tid & 63;
        for (int tau = wv; tau <= t; tau += 4) {
            float4 a = *(const float4*)(hallF + ((size_t)(tau*BS + b))*DIM + ln*4);
            float e = a.x*qdS[ln*4] + a.y*qdS[ln*4+1] + a.z*qdS[ln*4+2] + a.w*qdS[ln*4+3];
#pragma unroll
            for (int o=32;o>0;o>>=1) e += __shfl_down(e, o);
            if (ln == 0) adS[tau] = __expf(e);
        }
    }
    __syncthreads();
    if (tid < 64) {
        float v = (tid <= t) ? adS[tid] : 0.f;
#pragma unroll
        for (int o=32;o>0;o>>=1) v += __shfl_down(v, o);
        if (tid == 0) misc[1] = 1.f/v;
    }
    __syncthreads();
    float cd = 0.f;
    for (int tau = 0; tau <= t; ++tau)
        cd += adS[tau] * hallF[((size_t)(tau*BS + b))*DIM + tid];
    cd *= misc[1];
    if (t == 0) cd = 0.f;

    const float hd = hS[tid];
    const size_t fr = ((size_t)t*BS + b)*768;
    feat[fr + tid]       = (bf16_t)hd;
    feat[fr + 256 + tid] = (bf16_t)ce;
    feat[fr + 512 + tid] = (bf16_t)cd;
    float pw = hd*wu[tid] + ce*wu[256 + tid] + cd*wu[512 + tid];
#pragma unroll
    for (int o=32;o>0;o>>=1) pw += __shfl_down(pw, o);
    if ((tid & 63) == 0) red[tid>>6] = pw;
    __syncthreads();
    if (tid == 0) {
        float s = red[0]+red[1]+red[2]+red[3];
        ps[t*BS + b] = 1.f/(1.f+__expf(-(s + bu[0])));
    }
}

// ---------------- fused: attention tail (blocks 0-383, critical path, dispatched
// first) + W_out = tanh(W_emb @ W_proj) tiles (blocks 384-1883, backfill idle CUs).
// W_out is consumed only by the following mode-3 GEMM, so ordering is preserved.
__global__ __launch_bounds__(256) void k_attnw(
    const float* __restrict__ expE, const bf16_t* __restrict__ heT,
    const float* __restrict__ hallF, const bf16_t* __restrict__ qdG,
    const float* __restrict__ wu, const float* __restrict__ bu,
    bf16_t* __restrict__ feat, float* __restrict__ Ae, float* __restrict__ ps,
    const float* __restrict__ Wemb, const bf16_t* __restrict__ wprojT,
    bf16_t* __restrict__ woutB)
{
    __shared__ __align__(16) char shb[20480];
    if (blockIdx.x < NROW) {
        attn_body(shb, blockIdx.x, threadIdx.x, expE, heT, hallF, qdG, wu, bu, feat, Ae, ps);
        return;
    }
    gemm_tile(threadIdx.x, (bf16_t*)shb, (bf16_t*)(shb + 10240), nullptr, Wemb, wprojT,
              blockIdx.x - NROW, 768, 256, 6, 1,
              nullptr, woutB, nullptr, nullptr, nullptr, nullptr);
}

// ---------------- final: scale row by ps[r]/rsum[r], then copy-scatter ---------
__global__ __launch_bounds__(256) void k_final(
    float* __restrict__ out, const float* __restrict__ rsum,
    const float* __restrict__ ps, const int* __restrict__ src,
    const float* __restrict__ Ae)
{
    const int r = blockIdx.x;        // r = t*BS + b
    const int b = r & (BS-1);
    const float p  = ps[r];
    const float sc = p / rsum[r];
    float4* o4 = (float4*)(out + (size_t)r*VOCABN);
    for (int i = threadIdx.x; i < VOCABN/4; i += 256) {
        float4 v = o4[i];
        v.x*=sc; v.y*=sc; v.z*=sc; v.w*=sc;
        o4[i] = v;
    }
    __syncthreads();   // row fully scaled before scatter into it
    for (int s = threadIdx.x; s < SRC; s += 256) {
        const int v = src[s*BS + b];
        atomicAdd(&out[(size_t)r*VOCABN + v], Ae[(size_t)r*SRC + s] * p);
    }
}

// ---------------- workspace layout (bytes, 16B-aligned) ----------------
#define O_WHH    0u
#define O_WADT   524288u
#define O_HEBF   655360u
#define O_HET    3932160u
#define O_KE     7208960u
#define O_WAE    10485760u
#define O_WPROJT 10616832u
#define O_WIH    11010048u
#define O_EMBA   11534336u
#define O_WOUT   11730944u
#define O_XG     60882944u
#define O_HALLF  62455808u
#define O_HALLB  62849024u
#define O_QD     63045632u
#define O_EXPE   63242240u
#define O_FEAT   63856640u
#define O_AE     64446464u
#define O_PS     65060864u
#define O_RSUM   65063936u   // 1536 B, zeroed each call

extern "C" void kernel_launch(void* const* d_in, const int* in_sizes, int n_in,
                              void* d_out, int out_size, void* d_ws, size_t ws_size,
                              hipStream_t stream)
{
    const int*   inputs = (const int*)  d_in[0];
    const int*   src    = (const int*)  d_in[1];
    const float* h_e    = (const float*)d_in[2];
    const float* h0     = (const float*)d_in[3];
    const float* c0     = (const float*)d_in[4];
    const float* W_emb  = (const float*)d_in[5];
    const float* W_ih   = (const float*)d_in[6];
    const float* b_ih   = (const float*)d_in[7];
    const float* W_hh   = (const float*)d_in[8];
    const float* b_hh   = (const float*)d_in[9];
    const float* W_ae   = (const float*)d_in[10];
    const float* W_ad   = (const float*)d_in[11];
    const float* W_proj = (const float*)d_in[12];
    const float* W_u    = (const float*)d_in[13];
    const float* b_u    = (const float*)d_in[14];
    const float* b_out  = (const float*)d_in[15];
    const int*   pad_id = (const int*)  d_in[16];

    char* w = (char*)d_ws;
    bf16_t* whh_bf  = (bf16_t*)(w + O_WHH);
    bf16_t* wadT_bf = (bf16_t*)(w + O_WADT);
    bf16_t* he_bf   = (bf16_t*)(w + O_HEBF);
    bf16_t* heT_bf  = (bf16_t*)(w + O_HET);
    bf16_t* ke_bf   = (bf16_t*)(w + O_KE);
    bf16_t* wae_bf  = (bf16_t*)(w + O_WAE);
    bf16_t* wprojT  = (bf16_t*)(w + O_WPROJT);
    bf16_t* wih_bf  = (bf16_t*)(w + O_WIH);
    bf16_t* embA_bf = (bf16_t*)(w + O_EMBA);
    bf16_t* wout_bf = (bf16_t*)(w + O_WOUT);
    float*  xg      = (float*) (w + O_XG);      // holds xgT: [row][d][gate]
    float*  hallF   = (float*) (w + O_HALLF);
    bf16_t* hallB   = (bf16_t*)(w + O_HALLB);
    bf16_t* qdG     = (bf16_t*)(w + O_QD);
    float*  expE    = (float*) (w + O_EXPE);
    bf16_t* feat_bf = (bf16_t*)(w + O_FEAT);
    float*  Ae      = (float*) (w + O_AE);
    float*  ps      = (float*) (w + O_PS);
    float*  rsum    = (float*) (w + O_RSUM);
    float*  out     = (float*)d_out;

    k_prep<<<1024, 256, 0, stream>>>(W_hh, W_ad, h_e, W_emb, W_proj, W_ae, W_ih, inputs,
                                     whh_bf, wadT_bf, he_bf, heT_bf,
                                     wae_bf, wih_bf, wprojT, embA_bf);
    hipMemsetAsync(w + O_RSUM, 0, 1536, stream);
    // xgT (mode 4, 24 tiles) + ke (mode 2, 100 tiles) in one launch
    k_gemm2<<<124, 256, 0, stream>>>(embA_bf, wih_bf, xg, b_ih, b_hh,
                                     he_bf, wae_bf, ke_bf);
    // sequential LSTM chain (standalone, measured-good codegen)
    k_lstm<<<1, 512, 0, stream>>>(whh_bf, xg, h0, c0, hallF, hallB);
    // fused escore (blocks 0-383) + qd GEMM (blocks 384-389)
    k_esq<<<NROW + 6, 256, 0, stream>>>(ke_bf, hallF, expE, hallB, wadT_bf, qdG);
    // fused attention tail (0-383) + W_out GEMM (384-1883)
    k_attnw<<<NROW + 1500, 256, 0, stream>>>(expE, heT_bf, hallF, qdG, W_u, b_u,
                                             feat_bf, Ae, ps,
                                             W_emb, wprojT, wout_bf);
    // exp(logits + b_out), pad -> 0, + fused row sums  (M=384, N=32000, K=768)
    k_gemm<<<750, 256, 0, stream>>>(feat_bf, nullptr, wout_bf, NROW, VOCABN, 768, 250, 3,
                                    out, nullptr, b_out, nullptr, pad_id, rsum);
    // scale + copy-scatter, one block per row
    k_final<<<NROW, 256, 0, stream>>>(out, rsum, ps, src, Ae);
}

// Round 4
// 513.474 us; speedup vs baseline: 1.0668x; 1.0118x over previous
//
#include <hip/hip_runtime.h>
#include <cstdint>
#include <cstddef>

// ---------------- problem constants ----------------
#define TGT   24
#define BS    16
#define SRC   400
#define VOCABN 32000
#define DIM   256
#define NROW  (TGT*BS)   // 384

typedef __bf16 bf16_t;
typedef __bf16 v8bf __attribute__((ext_vector_type(8)));
typedef float  v4f  __attribute__((ext_vector_type(4)));

__device__ __forceinline__ float fast_tanh(float x) {
    // monotone, no NaN for large |x|: e->0 => -1, e->inf => +1
    float e = __expf(2.f*x);
    return 1.f - 2.f/(e + 1.f);
}

// ---------------- prep: dtype conversions / transposes / gather ----------------
__global__ void k_prep(const float* __restrict__ Whh, const float* __restrict__ Wad,
                       const float* __restrict__ he,  const float* __restrict__ Wemb,
                       const float* __restrict__ Wproj, const float* __restrict__ Wae,
                       const float* __restrict__ Wih, const int* __restrict__ inputs,
                       bf16_t* o_whh, bf16_t* o_wadT, bf16_t* o_he, bf16_t* o_heT,
                       bf16_t* o_wae, bf16_t* o_wih, bf16_t* o_wprojT, bf16_t* o_embA)
{
    const long S0=262144, S1=65536, S2=1638400, S3=1638400, S4=65536, S5=262144, S6=196608, S7=98304;
    const long total = S0+S1+S2+S3+S4+S5+S6+S7;
    for (long i = (long)blockIdx.x*blockDim.x + threadIdx.x; i < total;
         i += (long)gridDim.x*blockDim.x) {
        long j = i;
        if (j < S0) { o_whh[j] = (bf16_t)Whh[j]; continue; }           j -= S0;
        if (j < S1) { long n = j>>8, k = j&255; o_wadT[j] = (bf16_t)Wad[k*DIM + n]; continue; } j -= S1;
        if (j < S2) { o_he[j] = (bf16_t)he[j]; continue; }             j -= S2;
        if (j < S3) { // heT[b][d][s] = he[(s*BS+b)*DIM+d]
            long b = j / 102400, rem = j % 102400, d = rem / 400, s = rem % 400;
            o_heT[j] = (bf16_t)he[(s*BS + b)*DIM + d]; continue; }     j -= S3;
        if (j < S4) { o_wae[j] = (bf16_t)Wae[j]; continue; }           j -= S4;
        if (j < S5) { o_wih[j] = (bf16_t)Wih[j]; continue; }           j -= S5;
        if (j < S6) { long n = j>>8, k = j&255; o_wprojT[j] = (bf16_t)Wproj[k*768 + n]; continue; } j -= S6;
        { long r = j>>8, k = j&255; o_embA[j] = (bf16_t)Wemb[(long)inputs[r]*DIM + k]; }
    }
}

// ---------------- generic bf16 MFMA GEMM tile, 128x128, BK=32 (device body) ----
// C[M,N] = A[M,K] @ B[N,K]^T  (row-major, K-contiguous). A32!=null: A read fp32.
// mode 0: fp32 out + bias0 + bias1
// mode 1: bf16 out, tanh
// mode 2: bf16 out
// mode 3: exp(v+bias0), pad col -> 0, accumulate row sums into rsum (atomics)
// mode 4: fp32 out + bias0 + bias1, written TRANSPOSED-per-gate for the LSTM:
//         out[row*1024 + (col&255)*4 + (col>>8)]   (N must be 1024)
__device__ __forceinline__ void gemm_tile(
    const int tid, bf16_t* As, bf16_t* Bs,
    const bf16_t* __restrict__ A, const float* __restrict__ A32,
    const bf16_t* __restrict__ B,
    const int tileIdx, const int N, const int K, const int Ntiles, const int mode,
    float* __restrict__ outF, bf16_t* __restrict__ outB,
    const float* __restrict__ bias0, const float* __restrict__ bias1,
    const int* __restrict__ padp, float* __restrict__ rsum)
{
    const int mt   = tileIdx / Ntiles, nt = tileIdx % Ntiles;
    const int m0   = mt*128, n0 = nt*128;
    const int lane = tid & 63, wave = tid >> 6;
    const int wm   = wave >> 1, wn = wave & 1;
    const int quad = lane >> 4, l16 = lane & 15;

    v4f acc[4][4];
#pragma unroll
    for (int i=0;i<4;i++)
#pragma unroll
        for (int j=0;j<4;j++) acc[i][j] = (v4f){0.f,0.f,0.f,0.f};

    const int srow = tid >> 1, shalf = tid & 1;       // staging: 2 threads/row
    const bf16_t* Ag   = A   ? A   + (size_t)(m0+srow)*K + shalf*16 : nullptr;
    const float*  Ag32 = A32 ? A32 + (size_t)(m0+srow)*K + shalf*16 : nullptr;
    const bf16_t* Bg = B + (size_t)(n0+srow)*K + shalf*16;
    bf16_t* AsW = &As[srow*40 + shalf*16];
    bf16_t* BsW = &Bs[srow*40 + shalf*16];

    for (int kc = 0; kc < K; kc += 32) {
        __syncthreads();
        uint4 b0 = *(const uint4*)(Bg + kc);
        uint4 b1 = *(const uint4*)(Bg + kc + 8);
        if (A32) {
            float4 f0 = *(const float4*)(Ag32 + kc);
            float4 f1 = *(const float4*)(Ag32 + kc + 4);
            float4 f2 = *(const float4*)(Ag32 + kc + 8);
            float4 f3 = *(const float4*)(Ag32 + kc + 12);
            v8bf u0, u1;
            u0[0]=(bf16_t)f0.x; u0[1]=(bf16_t)f0.y; u0[2]=(bf16_t)f0.z; u0[3]=(bf16_t)f0.w;
            u0[4]=(bf16_t)f1.x; u0[5]=(bf16_t)f1.y; u0[6]=(bf16_t)f1.z; u0[7]=(bf16_t)f1.w;
            u1[0]=(bf16_t)f2.x; u1[1]=(bf16_t)f2.y; u1[2]=(bf16_t)f2.z; u1[3]=(bf16_t)f2.w;
            u1[4]=(bf16_t)f3.x; u1[5]=(bf16_t)f3.y; u1[6]=(bf16_t)f3.z; u1[7]=(bf16_t)f3.w;
            *(v8bf*)AsW = u0; *(v8bf*)(AsW+8) = u1;
        } else {
            uint4 a0 = *(const uint4*)(Ag + kc);
            uint4 a1 = *(const uint4*)(Ag + kc + 8);
            *(uint4*)AsW = a0; *(uint4*)(AsW+8) = a1;
        }
        *(uint4*)BsW = b0; *(uint4*)(BsW+8) = b1;
        __syncthreads();
        v8bf af[4], bb[4];
#pragma unroll
        for (int i=0;i<4;i++) {
            af[i] = *(const v8bf*)&As[(wm*64 + i*16 + l16)*40 + quad*8];
            bb[i] = *(const v8bf*)&Bs[(wn*64 + i*16 + l16)*40 + quad*8];
        }
#pragma unroll
        for (int i=0;i<4;i++)
#pragma unroll
            for (int j=0;j<4;j++)
                acc[i][j] = __builtin_amdgcn_mfma_f32_16x16x32_bf16(af[i], bb[j], acc[i][j], 0,0,0);
    }

    const int pad = padp ? *padp : -1;
    float* rs = (float*)As;          // LDS reuse for mode-3 row partial sums
    if (mode == 3) {
        __syncthreads();             // everyone past last As read
        if (tid < 128) rs[tid] = 0.f;
        __syncthreads();
    }
#pragma unroll
    for (int i=0;i<4;i++) {
        float rloc[4] = {0.f,0.f,0.f,0.f};
#pragma unroll
        for (int j=0;j<4;j++) {
#pragma unroll
            for (int r=0;r<4;r++) {
                const int gr = m0 + wm*64 + i*16 + quad*4 + r;   // C/D row = quad*4+reg
                const int gc = n0 + wn*64 + j*16 + l16;          // C/D col = lane&15
                const float v = acc[i][j][r];
                if (mode == 0)      outF[(size_t)gr*N + gc] = v + bias0[gc] + bias1[gc];
                else if (mode == 1) outB[(size_t)gr*N + gc] = (bf16_t)fast_tanh(v);
                else if (mode == 2) outB[(size_t)gr*N + gc] = (bf16_t)v;
                else if (mode == 4) outF[(size_t)gr*N + (gc & 255)*4 + (gc >> 8)] = v + bias0[gc] + bias1[gc];
                else {
                    float ex = (gc == pad) ? 0.f : __expf(v + bias0[gc]);
                    outF[(size_t)gr*N + gc] = ex;
                    rloc[r] += ex;
                }
            }
        }
        if (mode == 3) {
#pragma unroll
            for (int r=0;r<4;r++)
                atomicAdd(&rs[wm*64 + i*16 + quad*4 + r], rloc[r]);
        }
    }
    if (mode == 3) {
        __syncthreads();
        if (tid < 128) atomicAdd(&rsum[m0 + tid], rs[tid]);
    }
}

// standalone 256-thread GEMM wrapper (the big mode-3 logits GEMM)
__global__ __launch_bounds__(256) void k_gemm(
    const bf16_t* __restrict__ A, const float* __restrict__ A32,
    const bf16_t* __restrict__ B,
    int M, int N, int K, int Ntiles, int mode,
    float* outF, bf16_t* outB,
    const float* __restrict__ bias0, const float* __restrict__ bias1,
    const int* __restrict__ padp, float* __restrict__ rsum)
{
    (void)M;
    __shared__ bf16_t As[128*40];
    __shared__ bf16_t Bs[128*40];
    gemm_tile(threadIdx.x, As, Bs, A, A32, B, blockIdx.x, N, K, Ntiles, mode,
              outF, outB, bias0, bias1, padp, rsum);
}

// combined xg (mode 4, 24 tiles) + ke (mode 2, 100 tiles) — both depend only
// on k_prep, so they share one launch.
__global__ __launch_bounds__(256) void k_gemm2(
    const bf16_t* __restrict__ embA, const bf16_t* __restrict__ wih,
    float* __restrict__ xg, const float* __restrict__ b_ih, const float* __restrict__ b_hh,
    const bf16_t* __restrict__ heA, const bf16_t* __restrict__ waeB, bf16_t* __restrict__ keB)
{
    __shared__ bf16_t As[128*40];
    __shared__ bf16_t Bs[128*40];
    if (blockIdx.x < 24)
        gemm_tile(threadIdx.x, As, Bs, embA, nullptr, wih, blockIdx.x, 1024, 256, 8, 4,
                  xg, nullptr, b_ih, b_hh, nullptr, nullptr);
    else
        gemm_tile(threadIdx.x, As, Bs, heA, nullptr, waeB, blockIdx.x - 24, 256, 256, 2, 2,
                  nullptr, keB, nullptr, nullptr, nullptr, nullptr);
}

// ---------------- sequential LSTM chain: ONE block, ALL weights in registers ---
// STANDALONE kernel (co-compiling with gemm_tile measured +60us, rounds 1-3).
// 1024 threads = 16 waves (4/SIMD — 2x the old occupancy). Wave w owns d-slice
// [w*16, w*16+16) for ALL 4 gates: weights = 4 gates x 8 kc x v8bf = exactly
// 128 VGPR per lane -> the entire 512 KB W_hh lives in the block's registers.
// No LDS weight buffer, no in-loop weight loads. h double-buffered in LDS
// (34 KB): MFMA reads buf p, epilogue writes buf p^1 -> ONE barrier per step.
// xv (xgT pre-transposed [row][d][4gates]) issued at step top, hidden under MFMA.
__global__ __launch_bounds__(1024, 4) void k_lstm(
    const bf16_t* __restrict__ Whh, const float* __restrict__ xgT,
    const float* __restrict__ h0, const float* __restrict__ c0,
    float* __restrict__ hallF, bf16_t* __restrict__ hallB)
{
    __shared__ bf16_t hhi[2][16][264];
    __shared__ bf16_t hlo[2][16][264];

    const int tid = threadIdx.x;
    const int w = tid >> 6, lane = tid & 63;     // w: 0..15
    const int l16 = lane & 15, quad = lane >> 4;
    const int d = w*16 + l16;                    // this thread's d-column

    // ALL 4 gates' weights in registers: wreg[g][kc] (B-fragment layout:
    // lane l16 = weight row d, quad = k-subslice, per existing verified mapping)
    v8bf wreg[4][8];
#pragma unroll
    for (int g = 0; g < 4; ++g)
#pragma unroll
      for (int kc = 0; kc < 8; ++kc)
        wreg[g][kc] = *(const v8bf*)&Whh[(size_t)(g*256 + d)*DIM + kc*32 + quad*8];

    for (int i = tid; i < 4096; i += 1024) {
        int b = i >> 8, dd = i & 255;
        float v = h0[b*DIM + dd];
        bf16_t hi = (bf16_t)v;
        hhi[0][b][dd] = hi; hlo[0][b][dd] = (bf16_t)(v - (float)hi);
    }
    float c[4];
#pragma unroll
    for (int r = 0; r < 4; ++r)
        c[r] = c0[(quad*4 + r)*DIM + d];
    __syncthreads();

    int p = 0;
    for (int step = 0; step < TGT; ++step) {
        // xv prefetch: 4 coalesced float4, latency hidden under the MFMA loop
        float4 xv[4];
#pragma unroll
        for (int r = 0; r < 4; ++r)
            xv[r] = *(const float4*)(xgT + ((size_t)(step*BS + quad*4 + r)*DIM + d)*4);

        v4f acc[4];
#pragma unroll
        for (int g = 0; g < 4; ++g) acc[g] = (v4f){0.f,0.f,0.f,0.f};
#pragma unroll
        for (int kc = 0; kc < 8; ++kc) {
            v8bf ahi = *(const v8bf*)&hhi[p][l16][kc*32 + quad*8];
            v8bf alo = *(const v8bf*)&hlo[p][l16][kc*32 + quad*8];
#pragma unroll
            for (int g = 0; g < 4; ++g) {
                acc[g] = __builtin_amdgcn_mfma_f32_16x16x32_bf16(ahi, wreg[g][kc], acc[g], 0,0,0);
                acc[g] = __builtin_amdgcn_mfma_f32_16x16x32_bf16(alo, wreg[g][kc], acc[g], 0,0,0);
            }
        }
        // epilogue writes go to buffer p^1 -> no barrier needed before it
        // (laggard waves still reading buf p are untouched)
#pragma unroll
        for (int r = 0; r < 4; ++r) {
            const int b = quad*4 + r;            // C/D row = quad*4 + reg
            const float gi = acc[0][r] + xv[r].x;
            const float gf = acc[1][r] + xv[r].y;
            const float gg = acc[2][r] + xv[r].z;
            const float go = acc[3][r] + xv[r].w;
            const float si = 1.f/(1.f+__expf(-gi));
            const float sf = 1.f/(1.f+__expf(-gf));
            const float so = 1.f/(1.f+__expf(-go));
            const float cn = sf*c[r] + si*fast_tanh(gg);
            const float hn = so*fast_tanh(cn);
            c[r] = cn;
            const bf16_t hi = (bf16_t)hn;
            hhi[p^1][b][d] = hi; hlo[p^1][b][d] = (bf16_t)(hn - (float)hi);
            hallF[(size_t)(step*BS + b)*DIM + d] = hn;
            hallB[(size_t)(step*BS + b)*DIM + d] = hi;
        }
        __syncthreads();   // h(p^1) complete before next step reads it
        p ^= 1;
    }
}

// ---------------- expE[t,b,s] = exp(ke[s,b,:] . h[t,b,:]) (device body) --------
__device__ __forceinline__ void escore_body(const int blk, const int tid, float* hS,
    const bf16_t* __restrict__ ke, const float* __restrict__ hallF, float* __restrict__ expE)
{
    const int t = blk >> 4, b = blk & 15;
    hS[tid] = hallF[(size_t)(t*BS + b)*DIM + tid];
    __syncthreads();
    for (int s = tid; s < SRC; s += 256) {
        const v8bf* kp = (const v8bf*)(ke + ((size_t)s*BS + b)*DIM);
        float e = 0.f;
#pragma unroll 8
        for (int m=0;m<32;m++) {
            v8bf kv = kp[m];
#pragma unroll
            for (int i=0;i<8;i++) e += (float)kv[i]*hS[m*8+i];
        }
        expE[((size_t)t*BS + b)*SRC + s] = __expf(e);
    }
}

// fused escore + qd GEMM (qd = h_all @ W_attn_dec, 6 tiles)
__global__ __launch_bounds__(256) void k_esq(
    const bf16_t* __restrict__ ke, const float* __restrict__ hallF, float* __restrict__ expE,
    const bf16_t* __restrict__ hallB, const bf16_t* __restrict__ wadT, bf16_t* __restrict__ qdG)
{
    __shared__ __align__(16) char shb[20480];
    if (blockIdx.x < NROW) {
        escore_body(blockIdx.x, threadIdx.x, (float*)shb, ke, hallF, expE);
        return;
    }
    gemm_tile(threadIdx.x, (bf16_t*)shb, (bf16_t*)(shb + 10240), hallB, nullptr, wadT,
              blockIdx.x - NROW, 256, 256, 2, 2, nullptr, qdG, nullptr, nullptr, nullptr, nullptr);
}

// ---------------- per-(t,b) attention tail (device body) ----------------
__device__ void attn_body(char* sh, const int blk, const int tid,
    const float* __restrict__ expE, const bf16_t* __restrict__ heT,
    const float* __restrict__ hallF, const bf16_t* __restrict__ qdG,
    const float* __restrict__ wu, const float* __restrict__ bu,
    bf16_t* __restrict__ feat, float* __restrict__ Ae, float* __restrict__ ps)
{
    float* hS   = (float*)sh;        // 256
    float* qdS  = hS + 256;          // 256
    float* eeS  = qdS + 256;         // 400
    float* adS  = eeS + 400;         // 24
    float* red  = adS + 24;          // 4
    float* misc = red + 4;           // 2
    const int t = blk >> 4, b = blk & 15;

    hS[tid]  = hallF[(size_t)(t*BS + b)*DIM + tid];
    qdS[tid] = (float)qdG[(size_t)(t*BS + b)*DIM + tid];
    __syncthreads();

    for (int s = tid; s < SRC; s += 256) {
        float prev = 0.f;
        for (int tp = 0; tp < t; ++tp) prev += expE[((size_t)tp*BS + b)*SRC + s];
        float my = expE[((size_t)t*BS + b)*SRC + s];
        eeS[s] = (t == 0) ? my : my / prev;
    }
    __syncthreads();
    {   // esum
        float pa = 0.f;
        for (int s = tid; s < SRC; s += 256) pa += eeS[s];
#pragma unroll
        for (int o=32;o>0;o>>=1) pa += __shfl_down(pa, o);
        if ((tid & 63) == 0) red[tid>>6] = pa;
        __syncthreads();
        if (tid == 0) misc[0] = 1.f/(red[0]+red[1]+red[2]+red[3]);
        __syncthreads();
    }
    const float inv_es = misc[0];
    for (int s = tid; s < SRC; s += 256)
        Ae[((size_t)t*BS + b)*SRC + s] = eeS[s] * inv_es;

    float ce;
    {
        const v8bf* hp = (const v8bf*)(heT + ((size_t)b*DIM + tid)*SRC);
        float acc = 0.f;
#pragma unroll 10
        for (int m=0;m<50;m++) {
            v8bf hv = hp[m];
#pragma unroll
            for (int i=0;i<8;i++) acc += (float)hv[i]*eeS[m*8+i];
        }
        ce = acc * inv_es;
    }

    {
        const int wv = tid >> 6, ln = tid & 63;
        for (int tau = wv; tau <= t; tau += 4) {
            float4 a = *(const float4*)(hallF + ((size_t)(tau*BS + b))*DIM + ln*4);
            float e = a.x*qdS[ln*4] + a.y*qdS[ln*4+1] + a.z*qdS[ln*4+2] + a.w*qdS[ln*4+3];
#pragma unroll
            for (int o=32;o>0;o>>=1) e += __shfl_down(e, o);
            if (ln == 0) adS[tau] = __expf(e);
        }
    }
    __syncthreads();
    if (tid < 64) {
        float v = (tid <= t) ? adS[tid] : 0.f;
#pragma unroll
        for (int o=32;o>0;o>>=1) v += __shfl_down(v, o);
        if (tid == 0) misc[1] = 1.f/v;
    }
    __syncthreads();
    float cd = 0.f;
    for (int tau = 0; tau <= t; ++tau)
        cd += adS[tau] * hallF[((size_t)(tau*BS + b))*DIM + tid];
    cd *= misc[1];
    if (t == 0) cd = 0.f;

    const float hd = hS[tid];
    const size_t fr = ((size_t)t*BS + b)*768;
    feat[fr + tid]       = (bf16_t)hd;
    feat[fr + 256 + tid] = (bf16_t)ce;
    feat[fr + 512 + tid] = (bf16_t)cd;
    float pw = hd*wu[tid] + ce*wu[256 + tid] + cd*wu[512 + tid];
#pragma unroll
    for (int o=32;o>0;o>>=1) pw += __shfl_down(pw, o);
    if ((tid & 63) == 0) red[tid>>6] = pw;
    __syncthreads();
    if (tid == 0) {
        float s = red[0]+red[1]+red[2]+red[3];
        ps[t*BS + b] = 1.f/(1.f+__expf(-(s + bu[0])));
    }
}

// ---------------- fused: attention tail (blocks 0-383, critical path, dispatched
// first) + W_out = tanh(W_emb @ W_proj) tiles (blocks 384-1883, backfill idle CUs).
// W_out is consumed only by the following mode-3 GEMM, so ordering is preserved.
__global__ __launch_bounds__(256) void k_attnw(
    const float* __restrict__ expE, const bf16_t* __restrict__ heT,
    const float* __restrict__ hallF, const bf16_t* __restrict__ qdG,
    const float* __restrict__ wu, const float* __restrict__ bu,
    bf16_t* __restrict__ feat, float* __restrict__ Ae, float* __restrict__ ps,
    const float* __restrict__ Wemb, const bf16_t* __restrict__ wprojT,
    bf16_t* __restrict__ woutB)
{
    __shared__ __align__(16) char shb[20480];
    if (blockIdx.x < NROW) {
        attn_body(shb, blockIdx.x, threadIdx.x, expE, heT, hallF, qdG, wu, bu, feat, Ae, ps);
        return;
    }
    gemm_tile(threadIdx.x, (bf16_t*)shb, (bf16_t*)(shb + 10240), nullptr, Wemb, wprojT,
              blockIdx.x - NROW, 768, 256, 6, 1,
              nullptr, woutB, nullptr, nullptr, nullptr, nullptr);
}

// ---------------- final: scale row by ps[r]/rsum[r], then copy-scatter ---------
__global__ __launch_bounds__(256) void k_final(
    float* __restrict__ out, const float* __restrict__ rsum,
    const float* __restrict__ ps, const int* __restrict__ src,
    const float* __restrict__ Ae)
{
    const int r = blockIdx.x;        // r = t*BS + b
    const int b = r & (BS-1);
    const float p  = ps[r];
    const float sc = p / rsum[r];
    float4* o4 = (float4*)(out + (size_t)r*VOCABN);
    for (int i = threadIdx.x; i < VOCABN/4; i += 256) {
        float4 v = o4[i];
        v.x*=sc; v.y*=sc; v.z*=sc; v.w*=sc;
        o4[i] = v;
    }
    __syncthreads();   // row fully scaled before scatter into it
    for (int s = threadIdx.x; s < SRC; s += 256) {
        const int v = src[s*BS + b];
        atomicAdd(&out[(size_t)r*VOCABN + v], Ae[(size_t)r*SRC + s] * p);
    }
}

// ---------------- workspace layout (bytes, 16B-aligned) ----------------
#define O_WHH    0u
#define O_WADT   524288u
#define O_HEBF   655360u
#define O_HET    3932160u
#define O_KE     7208960u
#define O_WAE    10485760u
#define O_WPROJT 10616832u
#define O_WIH    11010048u
#define O_EMBA   11534336u
#define O_WOUT   11730944u
#define O_XG     60882944u
#define O_HALLF  62455808u
#define O_HALLB  62849024u
#define O_QD     63045632u
#define O_EXPE   63242240u
#define O_FEAT   63856640u
#define O_AE     64446464u
#define O_PS     65060864u
#define O_RSUM   65063936u   // 1536 B, zeroed each call

extern "C" void kernel_launch(void* const* d_in, const int* in_sizes, int n_in,
                              void* d_out, int out_size, void* d_ws, size_t ws_size,
                              hipStream_t stream)
{
    const int*   inputs = (const int*)  d_in[0];
    const int*   src    = (const int*)  d_in[1];
    const float* h_e    = (const float*)d_in[2];
    const float* h0     = (const float*)d_in[3];
    const float* c0     = (const float*)d_in[4];
    const float* W_emb  = (const float*)d_in[5];
    const float* W_ih   = (const float*)d_in[6];
    const float* b_ih   = (const float*)d_in[7];
    const float* W_hh   = (const float*)d_in[8];
    const float* b_hh   = (const float*)d_in[9];
    const float* W_ae   = (const float*)d_in[10];
    const float* W_ad   = (const float*)d_in[11];
    const float* W_proj = (const float*)d_in[12];
    const float* W_u    = (const float*)d_in[13];
    const float* b_u    = (const float*)d_in[14];
    const float* b_out  = (const float*)d_in[15];
    const int*   pad_id = (const int*)  d_in[16];

    char* w = (char*)d_ws;
    bf16_t* whh_bf  = (bf16_t*)(w + O_WHH);
    bf16_t* wadT_bf = (bf16_t*)(w + O_WADT);
    bf16_t* he_bf   = (bf16_t*)(w + O_HEBF);
    bf16_t* heT_bf  = (bf16_t*)(w + O_HET);
    bf16_t* ke_bf   = (bf16_t*)(w + O_KE);
    bf16_t* wae_bf  = (bf16_t*)(w + O_WAE);
    bf16_t* wprojT  = (bf16_t*)(w + O_WPROJT);
    bf16_t* wih_bf  = (bf16_t*)(w + O_WIH);
    bf16_t* embA_bf = (bf16_t*)(w + O_EMBA);
    bf16_t* wout_bf = (bf16_t*)(w + O_WOUT);
    float*  xg      = (float*) (w + O_XG);      // holds xgT: [row][d][gate]
    float*  hallF   = (float*) (w + O_HALLF);
    bf16_t* hallB   = (bf16_t*)(w + O_HALLB);
    bf16_t* qdG     = (bf16_t*)(w + O_QD);
    float*  expE    = (float*) (w + O_EXPE);
    bf16_t* feat_bf = (bf16_t*)(w + O_FEAT);
    float*  Ae      = (float*) (w + O_AE);
    float*  ps      = (float*) (w + O_PS);
    float*  rsum    = (float*) (w + O_RSUM);
    float*  out     = (float*)d_out;

    k_prep<<<1024, 256, 0, stream>>>(W_hh, W_ad, h_e, W_emb, W_proj, W_ae, W_ih, inputs,
                                     whh_bf, wadT_bf, he_bf, heT_bf,
                                     wae_bf, wih_bf, wprojT, embA_bf);
    hipMemsetAsync(w + O_RSUM, 0, 1536, stream);
    // xgT (mode 4, 24 tiles) + ke (mode 2, 100 tiles) in one launch
    k_gemm2<<<124, 256, 0, stream>>>(embA_bf, wih_bf, xg, b_ih, b_hh,
                                     he_bf, wae_bf, ke_bf);
    // sequential LSTM chain (standalone, all-register weights, 16 waves)
    k_lstm<<<1, 1024, 0, stream>>>(whh_bf, xg, h0, c0, hallF, hallB);
    // fused escore (blocks 0-383) + qd GEMM (blocks 384-389)
    k_esq<<<NROW + 6, 256, 0, stream>>>(ke_bf, hallF, expE, hallB, wadT_bf, qdG);
    // fused attention tail (0-383) + W_out GEMM (384-1883)
    k_attnw<<<NROW + 1500, 256, 0, stream>>>(expE, heT_bf, hallF, qdG, W_u, b_u,
                                             feat_bf, Ae, ps,
                                             W_emb, wprojT, wout_bf);
    // exp(logits + b_out), pad -> 0, + fused row sums  (M=384, N=32000, K=768)
    k_gemm<<<750, 256, 0, stream>>>(feat_bf, nullptr, wout_bf, NROW, VOCABN, 768, 250, 3,
                                    out, nullptr, b_out, nullptr, pad_id, rsum);
    // scale + copy-scatter, one block per row
    k_final<<<NROW, 256, 0, stream>>>(out, rsum, ps, src, Ae);
}

// Round 5
// 448.611 us; speedup vs baseline: 1.2210x; 1.1446x over previous
//
#include <hip/hip_runtime.h>
#include <cstdint>
#include <cstddef>

// ---------------- problem constants ----------------
#define TGT   24
#define BS    16
#define SRC   400
#define VOCABN 32000
#define DIM   256
#define NROW  (TGT*BS)   // 384
#define LSTM_NBLK 4

typedef __bf16 bf16_t;
typedef __bf16 v8bf __attribute__((ext_vector_type(8)));
typedef float  v4f  __attribute__((ext_vector_type(4)));

__device__ __forceinline__ float fast_tanh(float x) {
    // monotone, no NaN for large |x|: e->0 => -1, e->inf => +1
    float e = __expf(2.f*x);
    return 1.f - 2.f/(e + 1.f);
}

// ---------------- prep: dtype conversions / transposes / gather ----------------
__global__ void k_prep(const float* __restrict__ Whh, const float* __restrict__ Wad,
                       const float* __restrict__ he,  const float* __restrict__ Wemb,
                       const float* __restrict__ Wproj, const float* __restrict__ Wae,
                       const float* __restrict__ Wih, const int* __restrict__ inputs,
                       const float* __restrict__ h0,
                       bf16_t* o_whh, bf16_t* o_wadT, bf16_t* o_he, bf16_t* o_heT,
                       bf16_t* o_wae, bf16_t* o_wih, bf16_t* o_wprojT, bf16_t* o_embA,
                       bf16_t* o_hhi, bf16_t* o_hlo)
{
    const long S0=262144, S1=65536, S2=1638400, S3=1638400, S4=65536, S5=262144, S6=196608, S7=98304, S8=4096;
    const long total = S0+S1+S2+S3+S4+S5+S6+S7+S8;
    for (long i = (long)blockIdx.x*blockDim.x + threadIdx.x; i < total;
         i += (long)gridDim.x*blockDim.x) {
        long j = i;
        if (j < S0) { o_whh[j] = (bf16_t)Whh[j]; continue; }           j -= S0;
        if (j < S1) { long n = j>>8, k = j&255; o_wadT[j] = (bf16_t)Wad[k*DIM + n]; continue; } j -= S1;
        if (j < S2) { o_he[j] = (bf16_t)he[j]; continue; }             j -= S2;
        if (j < S3) { // heT[b][d][s] = he[(s*BS+b)*DIM+d]
            long b = j / 102400, rem = j % 102400, d = rem / 400, s = rem % 400;
            o_heT[j] = (bf16_t)he[(s*BS + b)*DIM + d]; continue; }     j -= S3;
        if (j < S4) { o_wae[j] = (bf16_t)Wae[j]; continue; }           j -= S4;
        if (j < S5) { o_wih[j] = (bf16_t)Wih[j]; continue; }           j -= S5;
        if (j < S6) { long n = j>>8, k = j&255; o_wprojT[j] = (bf16_t)Wproj[k*768 + n]; continue; } j -= S6;
        if (j < S7) { long r = j>>8, k = j&255; o_embA[j] = (bf16_t)Wemb[(long)inputs[r]*DIM + k]; continue; } j -= S7;
        { // h0 -> hi/lo bf16 split, [16][256]
          float v = h0[j];
          bf16_t hi = (bf16_t)v;
          o_hhi[j] = hi; o_hlo[j] = (bf16_t)(v - (float)hi); }
    }
}

// ---------------- generic bf16 MFMA GEMM tile, 128x128, BK=32 (device body) ----
// C[M,N] = A[M,K] @ B[N,K]^T  (row-major, K-contiguous). A32!=null: A read fp32.
// mode 0: fp32 out + bias0 + bias1
// mode 1: bf16 out, tanh
// mode 2: bf16 out
// mode 3: exp(v+bias0), pad col -> 0, accumulate row sums into rsum (atomics)
// mode 4: fp32 out + bias0 + bias1, written TRANSPOSED-per-gate for the LSTM:
//         out[row*1024 + (col&255)*4 + (col>>8)]   (N must be 1024)
__device__ __forceinline__ void gemm_tile(
    const int tid, bf16_t* As, bf16_t* Bs,
    const bf16_t* __restrict__ A, const float* __restrict__ A32,
    const bf16_t* __restrict__ B,
    const int tileIdx, const int N, const int K, const int Ntiles, const int mode,
    float* __restrict__ outF, bf16_t* __restrict__ outB,
    const float* __restrict__ bias0, const float* __restrict__ bias1,
    const int* __restrict__ padp, float* __restrict__ rsum)
{
    const int mt   = tileIdx / Ntiles, nt = tileIdx % Ntiles;
    const int m0   = mt*128, n0 = nt*128;
    const int lane = tid & 63, wave = tid >> 6;
    const int wm   = wave >> 1, wn = wave & 1;
    const int quad = lane >> 4, l16 = lane & 15;

    v4f acc[4][4];
#pragma unroll
    for (int i=0;i<4;i++)
#pragma unroll
        for (int j=0;j<4;j++) acc[i][j] = (v4f){0.f,0.f,0.f,0.f};

    const int srow = tid >> 1, shalf = tid & 1;       // staging: 2 threads/row
    const bf16_t* Ag   = A   ? A   + (size_t)(m0+srow)*K + shalf*16 : nullptr;
    const float*  Ag32 = A32 ? A32 + (size_t)(m0+srow)*K + shalf*16 : nullptr;
    const bf16_t* Bg = B + (size_t)(n0+srow)*K + shalf*16;
    bf16_t* AsW = &As[srow*40 + shalf*16];
    bf16_t* BsW = &Bs[srow*40 + shalf*16];

    for (int kc = 0; kc < K; kc += 32) {
        __syncthreads();
        uint4 b0 = *(const uint4*)(Bg + kc);
        uint4 b1 = *(const uint4*)(Bg + kc + 8);
        if (A32) {
            float4 f0 = *(const float4*)(Ag32 + kc);
            float4 f1 = *(const float4*)(Ag32 + kc + 4);
            float4 f2 = *(const float4*)(Ag32 + kc + 8);
            float4 f3 = *(const float4*)(Ag32 + kc + 12);
            v8bf u0, u1;
            u0[0]=(bf16_t)f0.x; u0[1]=(bf16_t)f0.y; u0[2]=(bf16_t)f0.z; u0[3]=(bf16_t)f0.w;
            u0[4]=(bf16_t)f1.x; u0[5]=(bf16_t)f1.y; u0[6]=(bf16_t)f1.z; u0[7]=(bf16_t)f1.w;
            u1[0]=(bf16_t)f2.x; u1[1]=(bf16_t)f2.y; u1[2]=(bf16_t)f2.z; u1[3]=(bf16_t)f2.w;
            u1[4]=(bf16_t)f3.x; u1[5]=(bf16_t)f3.y; u1[6]=(bf16_t)f3.z; u1[7]=(bf16_t)f3.w;
            *(v8bf*)AsW = u0; *(v8bf*)(AsW+8) = u1;
        } else {
            uint4 a0 = *(const uint4*)(Ag + kc);
            uint4 a1 = *(const uint4*)(Ag + kc + 8);
            *(uint4*)AsW = a0; *(uint4*)(AsW+8) = a1;
        }
        *(uint4*)BsW = b0; *(uint4*)(BsW+8) = b1;
        __syncthreads();
        v8bf af[4], bb[4];
#pragma unroll
        for (int i=0;i<4;i++) {
            af[i] = *(const v8bf*)&As[(wm*64 + i*16 + l16)*40 + quad*8];
            bb[i] = *(const v8bf*)&Bs[(wn*64 + i*16 + l16)*40 + quad*8];
        }
#pragma unroll
        for (int i=0;i<4;i++)
#pragma unroll
            for (int j=0;j<4;j++)
                acc[i][j] = __builtin_amdgcn_mfma_f32_16x16x32_bf16(af[i], bb[j], acc[i][j], 0,0,0);
    }

    const int pad = padp ? *padp : -1;
    float* rs = (float*)As;          // LDS reuse for mode-3 row partial sums
    if (mode == 3) {
        __syncthreads();             // everyone past last As read
        if (tid < 128) rs[tid] = 0.f;
        __syncthreads();
    }
#pragma unroll
    for (int i=0;i<4;i++) {
        float rloc[4] = {0.f,0.f,0.f,0.f};
#pragma unroll
        for (int j=0;j<4;j++) {
#pragma unroll
            for (int r=0;r<4;r++) {
                const int gr = m0 + wm*64 + i*16 + quad*4 + r;   // C/D row = quad*4+reg
                const int gc = n0 + wn*64 + j*16 + l16;          // C/D col = lane&15
                const float v = acc[i][j][r];
                if (mode == 0)      outF[(size_t)gr*N + gc] = v + bias0[gc] + bias1[gc];
                else if (mode == 1) outB[(size_t)gr*N + gc] = (bf16_t)fast_tanh(v);
                else if (mode == 2) outB[(size_t)gr*N + gc] = (bf16_t)v;
                else if (mode == 4) outF[(size_t)gr*N + (gc & 255)*4 + (gc >> 8)] = v + bias0[gc] + bias1[gc];
                else {
                    float ex = (gc == pad) ? 0.f : __expf(v + bias0[gc]);
                    outF[(size_t)gr*N + gc] = ex;
                    rloc[r] += ex;
                }
            }
        }
        if (mode == 3) {
#pragma unroll
            for (int r=0;r<4;r++)
                atomicAdd(&rs[wm*64 + i*16 + quad*4 + r], rloc[r]);
        }
    }
    if (mode == 3) {
        __syncthreads();
        if (tid < 128) atomicAdd(&rsum[m0 + tid], rs[tid]);
    }
}

// standalone 256-thread GEMM wrapper (the big mode-3 logits GEMM)
__global__ __launch_bounds__(256) void k_gemm(
    const bf16_t* __restrict__ A, const float* __restrict__ A32,
    const bf16_t* __restrict__ B,
    int M, int N, int K, int Ntiles, int mode,
    float* outF, bf16_t* outB,
    const float* __restrict__ bias0, const float* __restrict__ bias1,
    const int* __restrict__ padp, float* __restrict__ rsum)
{
    (void)M;
    __shared__ bf16_t As[128*40];
    __shared__ bf16_t Bs[128*40];
    gemm_tile(threadIdx.x, As, Bs, A, A32, B, blockIdx.x, N, K, Ntiles, mode,
              outF, outB, bias0, bias1, padp, rsum);
}

// combined xg (mode 4, 24 tiles) + ke (mode 2, 100 tiles) — both depend only
// on k_prep, so they share one launch.
__global__ __launch_bounds__(256) void k_gemm2(
    const bf16_t* __restrict__ embA, const bf16_t* __restrict__ wih,
    float* __restrict__ xg, const float* __restrict__ b_ih, const float* __restrict__ b_hh,
    const bf16_t* __restrict__ heA, const bf16_t* __restrict__ waeB, bf16_t* __restrict__ keB)
{
    __shared__ bf16_t As[128*40];
    __shared__ bf16_t Bs[128*40];
    if (blockIdx.x < 24)
        gemm_tile(threadIdx.x, As, Bs, embA, nullptr, wih, blockIdx.x, 1024, 256, 8, 4,
                  xg, nullptr, b_ih, b_hh, nullptr, nullptr);
    else
        gemm_tile(threadIdx.x, As, Bs, heA, nullptr, waeB, blockIdx.x - 24, 256, 256, 2, 2,
                  nullptr, keB, nullptr, nullptr, nullptr, nullptr);
}

// ---------------- device-scope grid barrier (monotonic counter) ----------------
__device__ __forceinline__ void gridbar(int* bar, int target) {
    __syncthreads();
    if (threadIdx.x == 0) {
        __threadfence();   // release: publish this block's h stores device-wide
        __hip_atomic_fetch_add(bar, 1, __ATOMIC_ACQ_REL, __HIP_MEMORY_SCOPE_AGENT);
        while (__hip_atomic_load(bar, __ATOMIC_ACQUIRE, __HIP_MEMORY_SCOPE_AGENT) < target) { }
        __threadfence();   // acquire: invalidate stale L1/L2 before h reads
    }
    __syncthreads();
}

// ---------------- sequential LSTM chain: 4 cooperating CUs, reg-resident W_hh --
// Block k owns d-slice [k*64, k*64+64) for ALL 4 gates. Weights per wave:
// 2 coltiles x 8 kc x v8bf = 64 VGPR; 8 waves x 4 blocks = the whole 512 KB W_hh
// register-resident across 4 CUs (one CU can't: regfile 512 KB with zero slack —
// rounds 0-4 all stalled on per-step weight supply). Per step: h A-fragments
// loaded from global h (one ~700cy latency), 32 MFMA/wave, pre-activations
// exchanged via 16 KB LDS, elementwise on thread-owned (b,d), h_new published,
// ONE device-scope grid barrier. Cross-XCD visibility: __threadfence + agent-
// scope atomics (per guide §6 G16).
__global__ __launch_bounds__(512, 2) void k_lstm(
    const bf16_t* __restrict__ Whh, const float* __restrict__ xgT,
    const float* __restrict__ c0,
    bf16_t* __restrict__ hhiG, bf16_t* __restrict__ hloG,   // [16][256] each
    float* __restrict__ hallF, bf16_t* __restrict__ hallB,
    int* __restrict__ bar)
{
    __shared__ float gl[16][260];   // pre-activation exchange, padded

    const int tid = threadIdx.x;
    const int k = blockIdx.x;            // d-slice owner
    const int w = tid >> 6, lane = tid & 63;
    const int l16 = lane & 15, quad = lane >> 4;

    // B-fragments: wave w owns CU-local cols c in [w*32, w*32+32), ct in {0,1}
    // c -> gate g = c>>6, dd = c&63, weight row = g*256 + k*64 + dd
    v8bf wb[2][8];
#pragma unroll
    for (int ct = 0; ct < 2; ++ct) {
        const int c = w*32 + ct*16 + l16;
        const int row = (c >> 6)*256 + k*64 + (c & 63);
#pragma unroll
        for (int kc = 0; kc < 8; ++kc)
            wb[ct][kc] = *(const v8bf*)&Whh[(size_t)row*DIM + kc*32 + quad*8];
    }

    // elementwise ownership: li = tid + e*512 -> b = li>>6, dd = li&63
    float cst[2];
#pragma unroll
    for (int e = 0; e < 2; ++e) {
        const int li = tid + e*512;
        cst[e] = c0[(li >> 6)*DIM + k*64 + (li & 63)];
    }

    for (int step = 0; step < TGT; ++step) {
        // A-fragments straight from global h (hi+lo) — 16 loads, one latency
        v8bf ahi[8], alo[8];
#pragma unroll
        for (int kc = 0; kc < 8; ++kc) {
            ahi[kc] = *(const v8bf*)&hhiG[l16*DIM + kc*32 + quad*8];
            alo[kc] = *(const v8bf*)&hloG[l16*DIM + kc*32 + quad*8];
        }
        // xv: 4 gates of xg for the two owned elements (float4, coalesced)
        float4 xv[2];
#pragma unroll
        for (int e = 0; e < 2; ++e) {
            const int li = tid + e*512;
            const int b = li >> 6, dd = li & 63;
            xv[e] = *(const float4*)&xgT[((size_t)(step*BS + b)*DIM + k*64 + dd)*4];
        }

        v4f acc[2] = {(v4f){0.f,0.f,0.f,0.f}, (v4f){0.f,0.f,0.f,0.f}};
#pragma unroll
        for (int kc = 0; kc < 8; ++kc)
#pragma unroll
            for (int ct = 0; ct < 2; ++ct) {
                acc[ct] = __builtin_amdgcn_mfma_f32_16x16x32_bf16(ahi[kc], wb[ct][kc], acc[ct], 0,0,0);
                acc[ct] = __builtin_amdgcn_mfma_f32_16x16x32_bf16(alo[kc], wb[ct][kc], acc[ct], 0,0,0);
            }
        // exchange pre-activations: C row = quad*4+r (b), col = l16 (c-in-tile)
#pragma unroll
        for (int ct = 0; ct < 2; ++ct) {
            const int c = w*32 + ct*16 + l16;
#pragma unroll
            for (int r = 0; r < 4; ++r)
                gl[quad*4 + r][c] = acc[ct][r];
        }
        __syncthreads();
        // elementwise: thread owns (b, dd) and (b+8, dd)
#pragma unroll
        for (int e = 0; e < 2; ++e) {
            const int li = tid + e*512;
            const int b = li >> 6, dd = li & 63;
            const int d = k*64 + dd;
            const float gi = gl[b][dd]        + xv[e].x;
            const float gf = gl[b][64 + dd]   + xv[e].y;
            const float gg = gl[b][128 + dd]  + xv[e].z;
            const float go = gl[b][192 + dd]  + xv[e].w;
            const float si = 1.f/(1.f+__expf(-gi));
            const float sf = 1.f/(1.f+__expf(-gf));
            const float so = 1.f/(1.f+__expf(-go));
            const float cn = sf*cst[e] + si*fast_tanh(gg);
            const float hn = so*fast_tanh(cn);
            cst[e] = cn;
            const bf16_t hi = (bf16_t)hn;
            hhiG[b*DIM + d] = hi;
            hloG[b*DIM + d] = (bf16_t)(hn - (float)hi);
            hallF[(size_t)(step*BS + b)*DIM + d] = hn;
            hallB[(size_t)(step*BS + b)*DIM + d] = hi;
        }
        if (step < TGT-1) gridbar(bar, (step+1)*LSTM_NBLK);
    }
}

// ---------------- expE[t,b,s] = exp(ke[s,b,:] . h[t,b,:]) (device body) --------
__device__ __forceinline__ void escore_body(const int blk, const int tid, float* hS,
    const bf16_t* __restrict__ ke, const float* __restrict__ hallF, float* __restrict__ expE)
{
    const int t = blk >> 4, b = blk & 15;
    hS[tid] = hallF[(size_t)(t*BS + b)*DIM + tid];
    __syncthreads();
    for (int s = tid; s < SRC; s += 256) {
        const v8bf* kp = (const v8bf*)(ke + ((size_t)s*BS + b)*DIM);
        float e = 0.f;
#pragma unroll 8
        for (int m=0;m<32;m++) {
            v8bf kv = kp[m];
#pragma unroll
            for (int i=0;i<8;i++) e += (float)kv[i]*hS[m*8+i];
        }
        expE[((size_t)t*BS + b)*SRC + s] = __expf(e);
    }
}

// fused escore + qd GEMM (qd = h_all @ W_attn_dec, 6 tiles)
__global__ __launch_bounds__(256) void k_esq(
    const bf16_t* __restrict__ ke, const float* __restrict__ hallF, float* __restrict__ expE,
    const bf16_t* __restrict__ hallB, const bf16_t* __restrict__ wadT, bf16_t* __restrict__ qdG)
{
    __shared__ __align__(16) char shb[20480];
    if (blockIdx.x < NROW) {
        escore_body(blockIdx.x, threadIdx.x, (float*)shb, ke, hallF, expE);
        return;
    }
    gemm_tile(threadIdx.x, (bf16_t*)shb, (bf16_t*)(shb + 10240), hallB, nullptr, wadT,
              blockIdx.x - NROW, 256, 256, 2, 2, nullptr, qdG, nullptr, nullptr, nullptr, nullptr);
}

// ---------------- per-(t,b) attention tail (device body) ----------------
__device__ void attn_body(char* sh, const int blk, const int tid,
    const float* __restrict__ expE, const bf16_t* __restrict__ heT,
    const float* __restrict__ hallF, const bf16_t* __restrict__ qdG,
    const float* __restrict__ wu, const float* __restrict__ bu,
    bf16_t* __restrict__ feat, float* __restrict__ Ae, float* __restrict__ ps)
{
    float* hS   = (float*)sh;        // 256
    float* qdS  = hS + 256;          // 256
    float* eeS  = qdS + 256;         // 400
    float* adS  = eeS + 400;         // 24
    float* red  = adS + 24;          // 4
    float* misc = red + 4;           // 2
    const int t = blk >> 4, b = blk & 15;

    hS[tid]  = hallF[(size_t)(t*BS + b)*DIM + tid];
    qdS[tid] = (float)qdG[(size_t)(t*BS + b)*DIM + tid];
    __syncthreads();

    for (int s = tid; s < SRC; s += 256) {
        float prev = 0.f;
        for (int tp = 0; tp < t; ++tp) prev += expE[((size_t)tp*BS + b)*SRC + s];
        float my = expE[((size_t)t*BS + b)*SRC + s];
        eeS[s] = (t == 0) ? my : my / prev;
    }
    __syncthreads();
    {   // esum
        float pa = 0.f;
        for (int s = tid; s < SRC; s += 256) pa += eeS[s];
#pragma unroll
        for (int o=32;o>0;o>>=1) pa += __shfl_down(pa, o);
        if ((tid & 63) == 0) red[tid>>6] = pa;
        __syncthreads();
        if (tid == 0) misc[0] = 1.f/(red[0]+red[1]+red[2]+red[3]);
        __syncthreads();
    }
    const float inv_es = misc[0];
    for (int s = tid; s < SRC; s += 256)
        Ae[((size_t)t*BS + b)*SRC + s] = eeS[s] * inv_es;

    float ce;
    {
        const v8bf* hp = (const v8bf*)(heT + ((size_t)b*DIM + tid)*SRC);
        float acc = 0.f;
#pragma unroll 10
        for (int m=0;m<50;m++) {
            v8bf hv = hp[m];
#pragma unroll
            for (int i=0;i<8;i++) acc += (float)hv[i]*eeS[m*8+i];
        }
        ce = acc * inv_es;
    }

    {
        const int wv = tid >> 6, ln = tid & 63;
        for (int tau = wv; tau <= t; tau += 4) {
            float4 a = *(const float4*)(hallF + ((size_t)(tau*BS + b))*DIM + ln*4);
            float e = a.x*qdS[ln*4] + a.y*qdS[ln*4+1] + a.z*qdS[ln*4+2] + a.w*qdS[ln*4+3];
#pragma unroll
            for (int o=32;o>0;o>>=1) e += __shfl_down(e, o);
            if (ln == 0) adS[tau] = __expf(e);
        }
    }
    __syncthreads();
    if (tid < 64) {
        float v = (tid <= t) ? adS[tid] : 0.f;
#pragma unroll
        for (int o=32;o>0;o>>=1) v += __shfl_down(v, o);
        if (tid == 0) misc[1] = 1.f/v;
    }
    __syncthreads();
    float cd = 0.f;
    for (int tau = 0; tau <= t; ++tau)
        cd += adS[tau] * hallF[((size_t)(tau*BS + b))*DIM + tid];
    cd *= misc[1];
    if (t == 0) cd = 0.f;

    const float hd = hS[tid];
    const size_t fr = ((size_t)t*BS + b)*768;
    feat[fr + tid]       = (bf16_t)hd;
    feat[fr + 256 + tid] = (bf16_t)ce;
    feat[fr + 512 + tid] = (bf16_t)cd;
    float pw = hd*wu[tid] + ce*wu[256 + tid] + cd*wu[512 + tid];
#pragma unroll
    for (int o=32;o>0;o>>=1) pw += __shfl_down(pw, o);
    if ((tid & 63) == 0) red[tid>>6] = pw;
    __syncthreads();
    if (tid == 0) {
        float s = red[0]+red[1]+red[2]+red[3];
        ps[t*BS + b] = 1.f/(1.f+__expf(-(s + bu[0])));
    }
}

// ---------------- fused: attention tail (blocks 0-383, critical path, dispatched
// first) + W_out = tanh(W_emb @ W_proj) tiles (blocks 384-1883, backfill idle CUs).
__global__ __launch_bounds__(256) void k_attnw(
    const float* __restrict__ expE, const bf16_t* __restrict__ heT,
    const float* __restrict__ hallF, const bf16_t* __restrict__ qdG,
    const float* __restrict__ wu, const float* __restrict__ bu,
    bf16_t* __restrict__ feat, float* __restrict__ Ae, float* __restrict__ ps,
    const float* __restrict__ Wemb, const bf16_t* __restrict__ wprojT,
    bf16_t* __restrict__ woutB)
{
    __shared__ __align__(16) char shb[20480];
    if (blockIdx.x < NROW) {
        attn_body(shb, blockIdx.x, threadIdx.x, expE, heT, hallF, qdG, wu, bu, feat, Ae, ps);
        return;
    }
    gemm_tile(threadIdx.x, (bf16_t*)shb, (bf16_t*)(shb + 10240), nullptr, Wemb, wprojT,
              blockIdx.x - NROW, 768, 256, 6, 1,
              nullptr, woutB, nullptr, nullptr, nullptr, nullptr);
}

// ---------------- final: scale row by ps[r]/rsum[r], then copy-scatter ---------
__global__ __launch_bounds__(256) void k_final(
    float* __restrict__ out, const float* __restrict__ rsum,
    const float* __restrict__ ps, const int* __restrict__ src,
    const float* __restrict__ Ae)
{
    const int r = blockIdx.x;        // r = t*BS + b
    const int b = r & (BS-1);
    const float p  = ps[r];
    const float sc = p / rsum[r];
    float4* o4 = (float4*)(out + (size_t)r*VOCABN);
    for (int i = threadIdx.x; i < VOCABN/4; i += 256) {
        float4 v = o4[i];
        v.x*=sc; v.y*=sc; v.z*=sc; v.w*=sc;
        o4[i] = v;
    }
    __syncthreads();   // row fully scaled before scatter into it
    for (int s = threadIdx.x; s < SRC; s += 256) {
        const int v = src[s*BS + b];
        atomicAdd(&out[(size_t)r*VOCABN + v], Ae[(size_t)r*SRC + s] * p);
    }
}

// ---------------- workspace layout (bytes, 16B-aligned) ----------------
#define O_WHH    0u
#define O_WADT   524288u
#define O_HEBF   655360u
#define O_HET    3932160u
#define O_KE     7208960u
#define O_WAE    10485760u
#define O_WPROJT 10616832u
#define O_WIH    11010048u
#define O_EMBA   11534336u
#define O_WOUT   11730944u
#define O_XG     60882944u
#define O_HALLF  62455808u
#define O_HALLB  62849024u
#define O_QD     63045632u
#define O_EXPE   63242240u   // first 16 KB double as hhiG/hloG during k_lstm
#define O_FEAT   63856640u
#define O_AE     64446464u
#define O_PS     65060864u
#define O_BAR    65062400u   // barrier counter (old scale slot), zeroed each call
#define O_RSUM   65063936u   // 1536 B, zeroed each call

extern "C" void kernel_launch(void* const* d_in, const int* in_sizes, int n_in,
                              void* d_out, int out_size, void* d_ws, size_t ws_size,
                              hipStream_t stream)
{
    const int*   inputs = (const int*)  d_in[0];
    const int*   src    = (const int*)  d_in[1];
    const float* h_e    = (const float*)d_in[2];
    const float* h0     = (const float*)d_in[3];
    const float* c0     = (const float*)d_in[4];
    const float* W_emb  = (const float*)d_in[5];
    const float* W_ih   = (const float*)d_in[6];
    const float* b_ih   = (const float*)d_in[7];
    const float* W_hh   = (const float*)d_in[8];
    const float* b_hh   = (const float*)d_in[9];
    const float* W_ae   = (const float*)d_in[10];
    const float* W_ad   = (const float*)d_in[11];
    const float* W_proj = (const float*)d_in[12];
    const float* W_u    = (const float*)d_in[13];
    const float* b_u    = (const float*)d_in[14];
    const float* b_out  = (const float*)d_in[15];
    const int*   pad_id = (const int*)  d_in[16];

    char* w = (char*)d_ws;
    bf16_t* whh_bf  = (bf16_t*)(w + O_WHH);
    bf16_t* wadT_bf = (bf16_t*)(w + O_WADT);
    bf16_t* he_bf   = (bf16_t*)(w + O_HEBF);
    bf16_t* heT_bf  = (bf16_t*)(w + O_HET);
    bf16_t* ke_bf   = (bf16_t*)(w + O_KE);
    bf16_t* wae_bf  = (bf16_t*)(w + O_WAE);
    bf16_t* wprojT  = (bf16_t*)(w + O_WPROJT);
    bf16_t* wih_bf  = (bf16_t*)(w + O_WIH);
    bf16_t* embA_bf = (bf16_t*)(w + O_EMBA);
    bf16_t* wout_bf = (bf16_t*)(w + O_WOUT);
    float*  xg      = (float*) (w + O_XG);      // holds xgT: [row][d][gate]
    float*  hallF   = (float*) (w + O_HALLF);
    bf16_t* hallB   = (bf16_t*)(w + O_HALLB);
    bf16_t* qdG     = (bf16_t*)(w + O_QD);
    float*  expE    = (float*) (w + O_EXPE);
    bf16_t* hhiG    = (bf16_t*)(w + O_EXPE);          // 8 KB, dead until k_esq
    bf16_t* hloG    = (bf16_t*)(w + O_EXPE + 8192);   // 8 KB
    bf16_t* feat_bf = (bf16_t*)(w + O_FEAT);
    float*  Ae      = (float*) (w + O_AE);
    float*  ps      = (float*) (w + O_PS);
    int*    bar     = (int*)   (w + O_BAR);
    float*  rsum    = (float*) (w + O_RSUM);
    float*  out     = (float*)d_out;

    k_prep<<<1024, 256, 0, stream>>>(W_hh, W_ad, h_e, W_emb, W_proj, W_ae, W_ih, inputs, h0,
                                     whh_bf, wadT_bf, he_bf, heT_bf,
                                     wae_bf, wih_bf, wprojT, embA_bf, hhiG, hloG);
    hipMemsetAsync(w + O_BAR, 0, 3072, stream);   // barrier counter + rsum
    // xgT (mode 4, 24 tiles) + ke (mode 2, 100 tiles) in one launch
    k_gemm2<<<124, 256, 0, stream>>>(embA_bf, wih_bf, xg, b_ih, b_hh,
                                     he_bf, wae_bf, ke_bf);
    // cooperative 4-CU LSTM chain, register-resident W_hh
    k_lstm<<<LSTM_NBLK, 512, 0, stream>>>(whh_bf, xg, c0, hhiG, hloG,
                                          hallF, hallB, bar);
    // fused escore (blocks 0-383) + qd GEMM (blocks 384-389)
    k_esq<<<NROW + 6, 256, 0, stream>>>(ke_bf, hallF, expE, hallB, wadT_bf, qdG);
    // fused attention tail (0-383) + W_out GEMM (384-1883)
    k_attnw<<<NROW + 1500, 256, 0, stream>>>(expE, heT_bf, hallF, qdG, W_u, b_u,
                                             feat_bf, Ae, ps,
                                             W_emb, wprojT, wout_bf);
    // exp(logits + b_out), pad -> 0, + fused row sums  (M=384, N=32000, K=768)
    k_gemm<<<750, 256, 0, stream>>>(feat_bf, nullptr, wout_bf, NROW, VOCABN, 768, 250, 3,
                                    out, nullptr, b_out, nullptr, pad_id, rsum);
    // scale + copy-scatter, one block per row
    k_final<<<NROW, 256, 0, stream>>>(out, rsum, ps, src, Ae);
}